// Round 12
// baseline (394.697 us; speedup 1.0000x reference)
//
#include <hip/hip_runtime.h>
#include <hip/hip_bf16.h>

#define N_NODES 100000
#define N_EDGES 500000
#define HID 128
#define NEG_SLOPE 0.2f
#define NB 98           // buckets of 1024 nodes: ceil(100000/1024)

typedef __attribute__((ext_vector_type(8))) short short8v;
typedef __attribute__((ext_vector_type(4))) short short4v;
typedef __attribute__((ext_vector_type(4))) float f32x4;

__device__ __forceinline__ short f2bf(float x) {
    union { float f; unsigned u; } v; v.f = x;
    unsigned r = v.u + 0x7fff + ((v.u >> 16) & 1);  // RNE
    return (short)(r >> 16);
}
__device__ __forceinline__ float bflo(unsigned u) {
    union { unsigned x; float f; } c; c.x = u << 16; return c.f;
}
__device__ __forceinline__ float bfhi(unsigned u) {
    union { unsigned x; float f; } c; c.x = u & 0xffff0000u; return c.f;
}
__device__ __forceinline__ float bfs(short s) {
    union { unsigned x; float f; } c; c.x = ((unsigned)(unsigned short)s) << 16; return c.f;
}
__device__ __forceinline__ float asf(unsigned u) {
    union { unsigned x; float f; } c; c.x = u; return c.f;
}

// ---------------- CSR build: binned two-level sort ----------------

__global__ __launch_bounds__(256) void k_bhist(const int* __restrict__ dst, int* __restrict__ bcnt) {
    int r = blockIdx.y, tid = threadIdx.x;
    int base = blockIdx.x * 4096;
    __shared__ int h[128];
    if (tid < 128) h[tid] = 0;
    __syncthreads();
    size_t eb = (size_t)r * N_EDGES;
    int lim = min(base + 4096, N_EDGES);
    for (int e = base + tid; e < lim; e += 256) atomicAdd(&h[dst[eb + e] >> 10], 1);
    __syncthreads();
    if (tid < NB && h[tid]) atomicAdd(&bcnt[r * NB + tid], h[tid]);
}

__global__ void k_bscan(const int* __restrict__ bcnt, int* __restrict__ bptr, int* __restrict__ bcur) {
    int r = blockIdx.x, lane = threadIdx.x;
    int carry = 0;
    for (int base = 0; base < NB; base += 64) {
        int i = base + lane;
        int c = (i < NB) ? bcnt[r * NB + i] : 0;
        int v = c;
        #pragma unroll
        for (int d = 1; d < 64; d <<= 1) { int t = __shfl_up(v, d); if (lane >= d) v += t; }
        int excl = carry + v - c;
        if (i < NB) { bptr[r * (NB + 1) + i] = excl; bcur[r * NB + i] = excl; }
        carry += __shfl(v, 63);
    }
    if (lane == 0) bptr[r * (NB + 1) + NB] = carry;
}

// bin edges into bucket regions of ebin packed as ((dst&1023)<<17 | src)
__global__ __launch_bounds__(256) void k_bin(const int* __restrict__ src, const int* __restrict__ dst,
                                             int* __restrict__ bcur, unsigned* __restrict__ ebin) {
    int r = blockIdx.y, tid = threadIdx.x;
    int base = blockIdx.x * 4096;
    __shared__ int cnt[128], incl[128], gb[128], wcur[128];
    __shared__ uint2 stage[4096];
    if (tid < 128) cnt[tid] = 0;
    __syncthreads();
    int myd[16], mys[16];
    size_t eb = (size_t)r * N_EDGES;
    #pragma unroll
    for (int i = 0; i < 16; i++) {
        int e = base + i * 256 + tid;
        if (e < N_EDGES) {
            int d = dst[eb + e];
            myd[i] = d; mys[i] = src[eb + e];
            atomicAdd(&cnt[d >> 10], 1);
        } else myd[i] = -1;
    }
    __syncthreads();
    if (tid < 128) incl[tid] = cnt[tid];
    __syncthreads();
    for (int d = 1; d < 128; d <<= 1) {
        int t = 0;
        if (tid < 128 && tid >= d) t = incl[tid - d];
        __syncthreads();
        if (tid < 128 && tid >= d) incl[tid] += t;
        __syncthreads();
    }
    if (tid < 128) {
        wcur[tid] = incl[tid] - cnt[tid];
        gb[tid] = (tid < NB && cnt[tid] > 0) ? atomicAdd(&bcur[r * NB + tid], cnt[tid]) : 0;
    }
    __syncthreads();
    #pragma unroll
    for (int i = 0; i < 16; i++) {
        if (myd[i] >= 0) {
            int bkt = myd[i] >> 10;
            int p = atomicAdd(&wcur[bkt], 1);
            stage[p] = make_uint2((unsigned)myd[i], (unsigned)mys[i]);
        }
    }
    __syncthreads();
    int tot = min(4096, N_EDGES - base);
    for (int i = tid; i < tot; i += 256) {
        uint2 u = stage[i];
        int bkt = (int)(u.x >> 10);
        int ex = incl[bkt] - cnt[bkt];
        ebin[eb + gb[bkt] + (i - ex)] = ((u.x & 1023u) << 17) | u.y;
    }
}

__global__ __launch_bounds__(256) void k_nhist(const unsigned* __restrict__ ebin,
                                               const int* __restrict__ bptr,
                                               int* __restrict__ rowptr) {
    int b = blockIdx.x, r = blockIdx.y, tid = threadIdx.x;
    __shared__ int cnt[1024];
    __shared__ int wsum[4];
    for (int i = tid; i < 1024; i += 256) cnt[i] = 0;
    __syncthreads();
    int es = bptr[r * (NB + 1) + b], ee = bptr[r * (NB + 1) + b + 1];
    size_t eb = (size_t)r * N_EDGES;
    for (int i = es + tid; i < ee; i += 256) atomicAdd(&cnt[(ebin[eb + i] >> 17) & 1023u], 1);
    __syncthreads();
    int b4 = tid * 4;
    int c0 = cnt[b4], c1 = cnt[b4 + 1], c2 = cnt[b4 + 2], c3 = cnt[b4 + 3];
    int ts = c0 + c1 + c2 + c3;
    int lane = tid & 63, wid = tid >> 6;
    int v = ts;
    #pragma unroll
    for (int d = 1; d < 64; d <<= 1) { int t = __shfl_up(v, d); if (lane >= d) v += t; }
    if (lane == 63) wsum[wid] = v;
    __syncthreads();
    int woff = 0;
    for (int w = 0; w < wid; w++) woff += wsum[w];
    int p = woff + v - ts;
    int node0 = b << 10;
    int rp = r * (N_NODES + 1);
    int nd;
    nd = node0 + b4;     if (nd < N_NODES) rowptr[rp + nd] = es + p; p += c0;
    nd = node0 + b4 + 1; if (nd < N_NODES) rowptr[rp + nd] = es + p; p += c1;
    nd = node0 + b4 + 2; if (nd < N_NODES) rowptr[rp + nd] = es + p; p += c2;
    nd = node0 + b4 + 3; if (nd < N_NODES) rowptr[rp + nd] = es + p;
    if (b == NB - 1 && tid == 0) rowptr[rp + N_NODES] = bptr[r * (NB + 1) + NB];
}

__global__ __launch_bounds__(256) void k_scat2(const unsigned* __restrict__ ebin,
                                               const int* __restrict__ bptr,
                                               const int* __restrict__ rowptr,
                                               int* __restrict__ csrc) {
    int b = blockIdx.x, r = blockIdx.y, tid = threadIdx.x;
    __shared__ int cnt[1024];
    __shared__ int rloc[1024];
    __shared__ int stage[8192];
    int node0 = b << 10;
    int rp = r * (N_NODES + 1);
    int rs = rowptr[rp + node0];
    for (int i = tid; i < 1024; i += 256) {
        cnt[i] = 0;
        int nd = node0 + i; if (nd > N_NODES) nd = N_NODES;
        rloc[i] = rowptr[rp + nd] - rs;
    }
    __syncthreads();
    int es = bptr[r * (NB + 1) + b], ee = bptr[r * (NB + 1) + b + 1];
    int sz = ee - es;
    size_t eb = (size_t)r * N_EDGES;
    if (sz <= 8192) {
        for (int i = es + tid; i < ee; i += 256) {
            unsigned u = ebin[eb + i];
            int dl = (int)((u >> 17) & 1023u);
            int rk = atomicAdd(&cnt[dl], 1);
            stage[rloc[dl] + rk] = (int)(u & 0x1FFFFu);
        }
        __syncthreads();
        for (int i = tid; i < sz; i += 256) csrc[eb + rs + i] = stage[i];
    } else {
        for (int i = es + tid; i < ee; i += 256) {
            unsigned u = ebin[eb + i];
            int dl = (int)((u >> 17) & 1023u);
            int rk = atomicAdd(&cnt[dl], 1);
            csrc[eb + rs + rloc[dl] + rk] = (int)(u & 0x1FFFFu);
        }
    }
}

// ---------------- W prep: f32 [k][col] -> bf16 [col][k ^ ((col&7)<<3)] ----------------
__global__ void k_wprep(const float* __restrict__ Ws, short* __restrict__ Wt) {
    int i = blockIdx.x * blockDim.x + threadIdx.x;
    if (i < 6 * 16384) {
        int lr = i >> 14, rem = i & 16383, k = rem >> 7, col = rem & 127;
        Wt[lr * 16384 + col * 128 + (k ^ ((col & 7) << 3))] = f2bf(Ws[i]);
    }
}

// clf_W f32 [128 k][64 col] -> bf16 [col][k ^ ((col&7)<<3)]
__global__ void k_wprep2(const float* __restrict__ Wc, short* __restrict__ Wcb) {
    int i = blockIdx.x * blockDim.x + threadIdx.x;
    if (i < 8192) {
        int k = i >> 6, col = i & 63;
        Wcb[col * 128 + (k ^ ((col & 7) << 3))] = f2bf(Wc[i]);
    }
}

// ---------------- f32 -> bf16 bulk convert ----------------
__global__ void k_cvt(const float* __restrict__ in, short* __restrict__ out, int n) {
    int i = blockIdx.x * blockDim.x + threadIdx.x;
    int stride = gridDim.x * blockDim.x;
    for (int base = i * 8; base < n; base += stride * 8) {
        float4 x = *(const float4*)(in + base);
        float4 y = *(const float4*)(in + base + 4);
        short8v o;
        o[0] = f2bf(x.x); o[1] = f2bf(x.y); o[2] = f2bf(x.z); o[3] = f2bf(x.w);
        o[4] = f2bf(y.x); o[5] = f2bf(y.y); o[6] = f2bf(y.z); o[7] = f2bf(y.w);
        *(short8v*)(out + base) = o;
    }
}

// ---------------- MFMA GEMM over 3 relations in one dispatch: featb[r] bf16 + fused el/er ----------------
__global__ __launch_bounds__(256) void k_gemm3(const short* __restrict__ Abf,
                                               const short* __restrict__ Wt3,    // 3 x 16384, pre-swizzled
                                               const float* __restrict__ al3,    // [3][128]
                                               const float* __restrict__ ar3,    // [3][128]
                                               short* __restrict__ featb,        // [3][N*128]
                                               float4* __restrict__ elr,         // [3][N]
                                               int nrows) {
    __shared__ __align__(16) short Wl[128 * 128];
    int tid = threadIdx.x;
    int lane = tid & 63, wid = tid >> 6;
    int q = lane >> 4, j = lane & 15;
    int rowbase = blockIdx.x * 128 + wid * 32;

    // A fragments once (shared by all 3 relations)
    short8v a[2][4];
    #pragma unroll
    for (int rb = 0; rb < 2; rb++) {
        int row = rowbase + rb * 16 + j;
        const short* ap = Abf + (size_t)row * 128 + q * 8;
        bool ok = row < nrows;
        #pragma unroll
        for (int kk = 0; kk < 4; kk++)
            a[rb][kk] = ok ? *(const short8v*)(ap + kk * 32) : (short8v)0;
    }

    for (int cr = 0; cr < 3; cr++) {
        if (cr) __syncthreads();   // all waves done reading Wl before overwrite
        {
            const float4* srcv = (const float4*)(Wt3 + cr * 16384);
            float4* dstv = (float4*)Wl;
            #pragma unroll
            for (int i = 0; i < 8; i++) dstv[tid + i * 256] = srcv[tid + i * 256];
        }
        float alv[8], arv[8];
        #pragma unroll
        for (int cb = 0; cb < 8; cb++) {
            alv[cb] = al3[cr * 128 + cb * 16 + j];
            arv[cb] = ar3[cr * 128 + cb * 16 + j];
        }
        __syncthreads();

        f32x4 acc[2][8] = {};
        #pragma unroll
        for (int cb = 0; cb < 8; cb++) {
            int col = cb * 16 + j;
            const short* wp = Wl + col * 128;
            int sw = (col & 7) << 3;
            #pragma unroll
            for (int kk = 0; kk < 4; kk++) {
                short8v b = *(const short8v*)(wp + ((kk * 32 + q * 8) ^ sw));
                acc[0][cb] = __builtin_amdgcn_mfma_f32_16x16x32_bf16(a[0][kk], b, acc[0][cb], 0, 0, 0);
                acc[1][cb] = __builtin_amdgcn_mfma_f32_16x16x32_bf16(a[1][kk], b, acc[1][cb], 0, 0, 0);
            }
        }

        short* outB = featb + (size_t)cr * N_NODES * 128;
        #pragma unroll
        for (int rb = 0; rb < 2; rb++) {
            int row0 = rowbase + rb * 16 + q * 4;
            #pragma unroll
            for (int reg = 0; reg < 4; reg++) {
                int row = row0 + reg;
                if (row < nrows) {
                    short* op = outB + (size_t)row * 128 + j;
                    #pragma unroll
                    for (int cb = 0; cb < 8; cb++) op[cb * 16] = f2bf(acc[rb][cb][reg]);
                }
            }
        }

        // fused el/er
        float4* elro = elr + (size_t)cr * N_NODES;
        #pragma unroll
        for (int rb = 0; rb < 2; rb++) {
            float e0[4], e1[4], r0[4], r1[4];
            #pragma unroll
            for (int reg = 0; reg < 4; reg++) {
                float se0 = 0.f, se1 = 0.f, sr0 = 0.f, sr1 = 0.f;
                #pragma unroll
                for (int cb = 0; cb < 4; cb++) {
                    se0 += acc[rb][cb][reg] * alv[cb];
                    sr0 += acc[rb][cb][reg] * arv[cb];
                    se1 += acc[rb][cb + 4][reg] * alv[cb + 4];
                    sr1 += acc[rb][cb + 4][reg] * arv[cb + 4];
                }
                #pragma unroll
                for (int off = 1; off < 16; off <<= 1) {
                    se0 += __shfl_xor(se0, off);
                    se1 += __shfl_xor(se1, off);
                    sr0 += __shfl_xor(sr0, off);
                    sr1 += __shfl_xor(sr1, off);
                }
                e0[reg] = se0; e1[reg] = se1; r0[reg] = sr0; r1[reg] = sr1;
            }
            if (j < 4) {
                int row = rowbase + rb * 16 + q * 4 + j;
                if (row < nrows) {
                    float4 v;
                    v.x = j == 0 ? e0[0] : j == 1 ? e0[1] : j == 2 ? e0[2] : e0[3];
                    v.y = j == 0 ? e1[0] : j == 1 ? e1[1] : j == 2 ? e1[2] : e1[3];
                    v.z = j == 0 ? r0[0] : j == 1 ? r0[1] : j == 2 ? r0[2] : r0[3];
                    v.w = j == 0 ? r1[0] : j == 1 ? r1[1] : j == 2 ? r1[2] : r1[3];
                    elro[row] = v;
                }
            }
        }
    }
}

// ---------------- edge-parallel softmax weights: palpha (packed bf16 pair) + per-node 1/sum ----------------
// thread per (node, relation); CSR-contiguous writes. Sums the bf16-ROUNDED p values in linear
// order so results match what k_agg3 multiplies.
__global__ __launch_bounds__(256) void k_edgep(const float4* __restrict__ elr,   // [3][N]
                                               const int* __restrict__ rowptr,   // [3][N+1]
                                               const int* __restrict__ csrc,     // [3][E]
                                               unsigned* __restrict__ palpha,    // [3][E]
                                               float2* __restrict__ nsum,        // [3][N]
                                               int nrows) {
    int r = blockIdx.y;
    int v = blockIdx.x * 256 + threadIdx.x;
    if (v >= nrows) return;
    int beg = rowptr[r * (N_NODES + 1) + v], end = rowptr[r * (N_NODES + 1) + v + 1];
    float4 ev = elr[(size_t)r * N_NODES + v];
    size_t eb = (size_t)r * N_EDGES;
    float s0 = 0.f, s1 = 0.f;
    for (int i = beg; i < end; i++) {
        int s = csrc[eb + i];
        float4 es = elr[(size_t)r * N_NODES + s];
        float e0 = es.x + ev.z; e0 = e0 >= 0.f ? e0 : NEG_SLOPE * e0;
        float e1 = es.y + ev.w; e1 = e1 >= 0.f ? e1 : NEG_SLOPE * e1;
        short b0 = f2bf(__expf(e0)), b1 = f2bf(__expf(e1));
        palpha[eb + i] = ((unsigned)(unsigned short)b0) | (((unsigned)(unsigned short)b1) << 16);
        s0 += bfs(b0); s1 += bfs(b1);
    }
    nsum[(size_t)r * N_NODES + v] = make_float2(s0 > 0.f ? 1.0f / s0 : 0.f,
                                                s1 > 0.f ? 1.0f / s1 : 0.f);
}

// ---------------- merged 3-relation gather-aggregate (wave per dst node) ----------------
// softmax weights precomputed (palpha/nsum). Branchless 4-wide chunked gather loops.
__global__ __launch_bounds__(256) void k_agg3(const short* __restrict__ feat,    // [3][N*128]
                                              const unsigned* __restrict__ palpha,// [3][E]
                                              const float2* __restrict__ nsum,   // [3][N]
                                              const int* __restrict__ rowptr,    // [3][N+1]
                                              const int* __restrict__ csrc,      // [3][E]
                                              const float* __restrict__ bias,    // [3][128]
                                              short* __restrict__ outB, int nrows) {
    int wid = threadIdx.x >> 6, lane = threadIdx.x & 63;
    int v = (blockIdx.x << 2) + wid;
    if (v >= nrows) return;
    int c0 = lane << 1;
    bool lo = lane < 32;

    int beg[3], end[3], bc[3];
    #pragma unroll
    for (int r = 0; r < 3; r++) {
        beg[r] = rowptr[r * (N_NODES + 1) + v];
        end[r] = rowptr[r * (N_NODES + 1) + v + 1];
        bc[r] = min(64, end[r] - beg[r]);
    }

    int sv[3]; unsigned pk[3];
    #pragma unroll
    for (int r = 0; r < 3; r++) {
        bool val = lane < end[r] - beg[r];
        size_t idx = (size_t)r * N_EDGES + beg[r] + lane;
        sv[r] = val ? csrc[idx] : 0;
        pk[r] = val ? palpha[idx] : 0u;
    }

    float a0[3], a1[3];

    #pragma unroll
    for (int r = 0; r < 3; r++) {
        const short* fb = feat + (size_t)r * (N_NODES * 128);
        int nb = bc[r];
        float xa = 0.f, xb = 0.f, ya = 0.f, yb = 0.f;
        for (int j0 = 0; j0 < nb; j0 += 4) {
            int s0 = __builtin_amdgcn_readlane(sv[r], j0);
            int s1 = __builtin_amdgcn_readlane(sv[r], j0 + 1);
            int s2 = __builtin_amdgcn_readlane(sv[r], j0 + 2);
            int s3 = __builtin_amdgcn_readlane(sv[r], j0 + 3);
            unsigned b0 = (unsigned)__builtin_amdgcn_readlane((int)pk[r], j0);
            unsigned b1 = (unsigned)__builtin_amdgcn_readlane((int)pk[r], j0 + 1);
            unsigned b2 = (unsigned)__builtin_amdgcn_readlane((int)pk[r], j0 + 2);
            unsigned b3 = (unsigned)__builtin_amdgcn_readlane((int)pk[r], j0 + 3);
            unsigned u0 = *(const unsigned*)(fb + ((size_t)(unsigned)s0 << 7) + c0);
            unsigned u1 = *(const unsigned*)(fb + ((size_t)(unsigned)s1 << 7) + c0);
            unsigned u2 = *(const unsigned*)(fb + ((size_t)(unsigned)s2 << 7) + c0);
            unsigned u3 = *(const unsigned*)(fb + ((size_t)(unsigned)s3 << 7) + c0);
            float p0 = asf(lo ? (b0 << 16) : (b0 & 0xffff0000u));
            float p1 = asf(lo ? (b1 << 16) : (b1 & 0xffff0000u));
            float p2 = asf(lo ? (b2 << 16) : (b2 & 0xffff0000u));
            float p3 = asf(lo ? (b3 << 16) : (b3 & 0xffff0000u));
            xa += p0 * bflo(u0); xb += p0 * bfhi(u0);
            ya += p1 * bflo(u1); yb += p1 * bfhi(u1);
            xa += p2 * bflo(u2); xb += p2 * bfhi(u2);
            ya += p3 * bflo(u3); yb += p3 * bfhi(u3);
        }
        a0[r] = xa + ya; a1[r] = xb + yb;
    }

    // rare tail: degree > 64
    #pragma unroll
    for (int r = 0; r < 3; r++) {
        const short* fb = feat + (size_t)r * (N_NODES * 128);
        for (int base = beg[r] + 64; base < end[r]; base += 64) {
            int idx = base + lane;
            bool val = idx < end[r];
            int sv2 = val ? csrc[(size_t)r * N_EDGES + idx] : 0;
            unsigned pk2 = val ? palpha[(size_t)r * N_EDGES + idx] : 0u;
            int bc2 = min(64, end[r] - base);
            for (int k = 0; k < bc2; k++) {
                int ss = __builtin_amdgcn_readlane(sv2, k);
                unsigned pb = (unsigned)__builtin_amdgcn_readlane((int)pk2, k);
                float pp = asf(lo ? (pb << 16) : (pb & 0xffff0000u));
                unsigned u = *(const unsigned*)(fb + ((size_t)(unsigned)ss << 7) + c0);
                a0[r] += pp * bflo(u);
                a1[r] += pp * bfhi(u);
            }
        }
    }

    float t0 = bias[c0] + bias[128 + c0] + bias[256 + c0];
    float t1 = bias[c0 + 1] + bias[128 + c0 + 1] + bias[256 + c0 + 1];
    #pragma unroll
    for (int r = 0; r < 3; r++) {
        float2 iv = nsum[(size_t)r * N_NODES + v];
        float ii = lo ? iv.x : iv.y;
        t0 += a0[r] * ii;
        t1 += a1[r] * ii;
    }
    unsigned pko = ((unsigned)(unsigned short)f2bf(fmaxf(t0, 0.f))) |
                   (((unsigned)(unsigned short)f2bf(fmaxf(t1, 0.f))) << 16);
    *(unsigned*)(outB + (size_t)v * 128 + c0) = pko;
}

// ---------------- BN stats (bf16 relu'd input, vectorized) ----------------
__global__ __launch_bounds__(256) void k_bnstat(const short* __restrict__ h,
                                                float* __restrict__ sums, int nrows) {
    int tid = threadIdx.x;
    int cg = tid & 15, rgrp = tid >> 4;
    float s[8] = {}, q[8] = {};
    for (int row = blockIdx.x * 16 + rgrp; row < nrows; row += gridDim.x * 16) {
        short8v u = *(const short8v*)(h + (size_t)row * 128 + cg * 8);
        #pragma unroll
        for (int i = 0; i < 8; i++) {
            float x = bfs(u[i]);
            s[i] += x; q[i] += x * x;
        }
    }
    __shared__ float ls[16][128];
    __shared__ float lq[16][128];
    #pragma unroll
    for (int i = 0; i < 8; i++) { ls[rgrp][cg * 8 + i] = s[i]; lq[rgrp][cg * 8 + i] = q[i]; }
    __syncthreads();
    int t = tid;
    if (t < 128) {
        float ts = 0.f, tq = 0.f;
        #pragma unroll
        for (int g = 0; g < 16; g++) { ts += ls[g][t]; tq += lq[g][t]; }
        atomicAdd(&sums[t], ts);
        atomicAdd(&sums[128 + t], tq);
    }
}

// ---------------- classifier: BN-normalize (input pre-relu'd bf16) -> MFMA GEMM [N,128]x[128,64] ----------------
__global__ __launch_bounds__(256) void k_clf(const short* __restrict__ h,
                                             const float* __restrict__ sums,
                                             const float* __restrict__ bn_w,
                                             const float* __restrict__ bn_b,
                                             const short* __restrict__ Wcb,
                                             const float* __restrict__ cbias,
                                             float* __restrict__ out, int nrows) {
    __shared__ __align__(16) short Wl[64 * 128];
    __shared__ float2 bnp[128];
    int tid = threadIdx.x;
    {
        const float4* srcv = (const float4*)Wcb;
        float4* dstv = (float4*)Wl;
        #pragma unroll
        for (int i = 0; i < 4; i++) dstv[tid + i * 256] = srcv[tid + i * 256];
    }
    if (tid < 128) {
        float mu = sums[tid] / (float)nrows;
        float var = sums[128 + tid] / (float)nrows - mu * mu;
        float rs = rsqrtf(var + 1e-5f);
        float sc = bn_w[tid] * rs;
        bnp[tid] = make_float2(sc, bn_b[tid] - mu * sc);
    }
    __syncthreads();

    int lane = tid & 63, wid = tid >> 6;
    int q = lane >> 4, j = lane & 15;
    int rowbase = blockIdx.x * 128 + wid * 32;

    float cbv[4];
    #pragma unroll
    for (int cb = 0; cb < 4; cb++) cbv[cb] = cbias[cb * 16 + j];

    short8v a[2][4];
    #pragma unroll
    for (int rb = 0; rb < 2; rb++) {
        int row = rowbase + rb * 16 + j;
        bool ok = row < nrows;
        const short* hp = h + (size_t)row * 128 + q * 8;
        #pragma unroll
        for (int kk = 0; kk < 4; kk++) {
            short8v u = ok ? *(const short8v*)(hp + kk * 32) : (short8v)0;
            int k0 = kk * 32 + q * 8;
            short8v av;
            #pragma unroll
            for (int i = 0; i < 8; i++) {
                float2 bp = bnp[k0 + i];
                av[i] = f2bf(bfs(u[i]) * bp.x + bp.y);
            }
            a[rb][kk] = av;
        }
    }

    f32x4 acc[2][4] = {};
    #pragma unroll
    for (int cb = 0; cb < 4; cb++) {
        int col = cb * 16 + j;
        const short* wp = Wl + col * 128;
        int sw = (col & 7) << 3;
        #pragma unroll
        for (int kk = 0; kk < 4; kk++) {
            short8v b = *(const short8v*)(wp + ((kk * 32 + q * 8) ^ sw));
            acc[0][cb] = __builtin_amdgcn_mfma_f32_16x16x32_bf16(a[0][kk], b, acc[0][cb], 0, 0, 0);
            acc[1][cb] = __builtin_amdgcn_mfma_f32_16x16x32_bf16(a[1][kk], b, acc[1][cb], 0, 0, 0);
        }
    }

    #pragma unroll
    for (int rb = 0; rb < 2; rb++) {
        int row0 = rowbase + rb * 16 + q * 4;
        #pragma unroll
        for (int reg = 0; reg < 4; reg++) {
            int row = row0 + reg;
            if (row < nrows) {
                float* op = out + (size_t)row * 64 + j;
                #pragma unroll
                for (int cb = 0; cb < 4; cb++) op[cb * 16] = acc[rb][cb][reg] + cbv[cb];
            }
        }
    }
}

// ---------------- launch ----------------

extern "C" void kernel_launch(void* const* d_in, const int* in_sizes, int n_in,
                              void* d_out, int out_size, void* d_ws, size_t ws_size,
                              hipStream_t stream) {
    (void)in_sizes; (void)n_in; (void)out_size; (void)ws_size;
    const float* feat_in = (const float*)d_in[0];
    const float* Ws      = (const float*)d_in[1];
    const float* als     = (const float*)d_in[2];
    const float* ars     = (const float*)d_in[3];
    const float* bs      = (const float*)d_in[4];
    const float* bn_w    = (const float*)d_in[5];
    const float* bn_b    = (const float*)d_in[6];
    const float* clf_W   = (const float*)d_in[7];
    const float* clf_b   = (const float*)d_in[8];
    const int*   src     = (const int*)d_in[9];
    const int*   dst     = (const int*)d_in[10];
    float* out = (float*)d_out;

    const int N = N_NODES, E = N_EDGES;
    char* p = (char*)d_ws;
    auto carve = [&](size_t bytes) { char* q = p; p += (bytes + 255) & ~255ULL; return q; };
    int*      bcnt   = (int*)carve((size_t)3 * NB * 4);
    int*      bptr   = (int*)carve((size_t)3 * (NB + 1) * 4);
    int*      bcur   = (int*)carve((size_t)3 * NB * 4);
    int*      rowptr = (int*)carve((size_t)3 * (N + 1) * 4);
    int*      csrc   = (int*)carve((size_t)3 * E * 4);
    unsigned* ebin   = (unsigned*)carve((size_t)3 * E * 4);
    unsigned* palpha = (unsigned*)carve((size_t)3 * E * 4);
    float2*   nsum   = (float2*)carve((size_t)3 * N * 8);
    float4*   elr    = (float4*)carve((size_t)3 * N * 16);
    float*    bnsum  = (float*)carve(256 * 4);
    short*    Wtg    = (short*)carve((size_t)6 * 16384 * 2);
    short*    Wcb    = (short*)carve((size_t)8192 * 2);
    short*    hA     = (short*)carve((size_t)N * 128 * 2);
    short*    hB     = (short*)carve((size_t)N * 128 * 2);
    short*    featb  = (short*)carve((size_t)3 * N * 128 * 2);

    // weight prep + input conversion
    k_wprep<<<(6 * 16384 + 255) / 256, 256, 0, stream>>>(Ws, Wtg);
    k_wprep2<<<32, 256, 0, stream>>>(clf_W, Wcb);
    k_cvt<<<2048, 256, 0, stream>>>(feat_in, hA, N * 128);

    // CSR build via binned sort
    hipMemsetAsync(bcnt, 0, (size_t)3 * NB * 4, stream);
    dim3 gchunk((E + 4095) / 4096, 3);
    k_bhist<<<gchunk, 256, 0, stream>>>(dst, bcnt);
    k_bscan<<<3, 64, 0, stream>>>(bcnt, bptr, bcur);
    k_bin<<<gchunk, 256, 0, stream>>>(src, dst, bcur, ebin);
    dim3 gbkt(NB, 3);
    k_nhist<<<gbkt, 256, 0, stream>>>(ebin, bptr, rowptr);
    k_scat2<<<gbkt, 256, 0, stream>>>(ebin, bptr, rowptr, csrc);

    int gq = (N + 3) / 4;
    dim3 gep((N + 255) / 256, 3);
    for (int l = 0; l < 2; l++) {
        const short* hin = (l == 0) ? hA : hB;
        short* hout = (l == 0) ? hB : hA;
        k_gemm3<<<(N + 127) / 128, 256, 0, stream>>>(hin, Wtg + (size_t)l * 3 * 16384,
                                                     als + (size_t)l * 384, ars + (size_t)l * 384,
                                                     featb, elr, N);
        k_edgep<<<gep, 256, 0, stream>>>(elr, rowptr, csrc, palpha, nsum, N);
        k_agg3<<<gq, 256, 0, stream>>>(featb, palpha, nsum, rowptr, csrc,
                                       bs + (size_t)l * 384, hout, N);
    }

    // BN + classifier on hA (layer-2 output, relu'd bf16)
    hipMemsetAsync(bnsum, 0, 256 * 4, stream);
    k_bnstat<<<512, 256, 0, stream>>>(hA, bnsum, N);
    k_clf<<<(N + 127) / 128, 256, 0, stream>>>(hA, bnsum, bn_w, bn_b, Wcb, clf_b, out, N);
}

// Round 13
// 354.984 us; speedup vs baseline: 1.1119x; 1.1119x over previous
//
#include <hip/hip_runtime.h>
#include <hip/hip_bf16.h>

#define N_NODES 100000
#define N_EDGES 500000
#define HID 128
#define NEG_SLOPE 0.2f
#define NB 98           // buckets of 1024 nodes: ceil(100000/1024)

typedef __attribute__((ext_vector_type(8))) short short8v;
typedef __attribute__((ext_vector_type(4))) short short4v;
typedef __attribute__((ext_vector_type(4))) float f32x4;

__device__ __forceinline__ short f2bf(float x) {
    union { float f; unsigned u; } v; v.f = x;
    unsigned r = v.u + 0x7fff + ((v.u >> 16) & 1);  // RNE
    return (short)(r >> 16);
}
__device__ __forceinline__ float bflo(unsigned u) {
    union { unsigned x; float f; } c; c.x = u << 16; return c.f;
}
__device__ __forceinline__ float bfhi(unsigned u) {
    union { unsigned x; float f; } c; c.x = u & 0xffff0000u; return c.f;
}
__device__ __forceinline__ float bfs(short s) {
    union { unsigned x; float f; } c; c.x = ((unsigned)(unsigned short)s) << 16; return c.f;
}
__device__ __forceinline__ float asf(unsigned u) {
    union { unsigned x; float f; } c; c.x = u; return c.f;
}
__device__ __forceinline__ float rlf(float x, int i) {
    return asf((unsigned)__builtin_amdgcn_readlane((int)__float_as_uint(x), i));
}

// ---------------- CSR build: binned two-level sort ----------------

__global__ __launch_bounds__(256) void k_bhist(const int* __restrict__ dst, int* __restrict__ bcnt) {
    int r = blockIdx.y, tid = threadIdx.x;
    int base = blockIdx.x * 4096;
    __shared__ int h[128];
    if (tid < 128) h[tid] = 0;
    __syncthreads();
    size_t eb = (size_t)r * N_EDGES;
    int lim = min(base + 4096, N_EDGES);
    for (int e = base + tid; e < lim; e += 256) atomicAdd(&h[dst[eb + e] >> 10], 1);
    __syncthreads();
    if (tid < NB && h[tid]) atomicAdd(&bcnt[r * NB + tid], h[tid]);
}

__global__ void k_bscan(const int* __restrict__ bcnt, int* __restrict__ bptr, int* __restrict__ bcur) {
    int r = blockIdx.x, lane = threadIdx.x;
    int carry = 0;
    for (int base = 0; base < NB; base += 64) {
        int i = base + lane;
        int c = (i < NB) ? bcnt[r * NB + i] : 0;
        int v = c;
        #pragma unroll
        for (int d = 1; d < 64; d <<= 1) { int t = __shfl_up(v, d); if (lane >= d) v += t; }
        int excl = carry + v - c;
        if (i < NB) { bptr[r * (NB + 1) + i] = excl; bcur[r * NB + i] = excl; }
        carry += __shfl(v, 63);
    }
    if (lane == 0) bptr[r * (NB + 1) + NB] = carry;
}

// bin edges into bucket regions of ebin packed as ((dst&1023)<<17 | src)
__global__ __launch_bounds__(256) void k_bin(const int* __restrict__ src, const int* __restrict__ dst,
                                             int* __restrict__ bcur, unsigned* __restrict__ ebin) {
    int r = blockIdx.y, tid = threadIdx.x;
    int base = blockIdx.x * 4096;
    __shared__ int cnt[128], incl[128], gb[128], wcur[128];
    __shared__ uint2 stage[4096];
    if (tid < 128) cnt[tid] = 0;
    __syncthreads();
    int myd[16], mys[16];
    size_t eb = (size_t)r * N_EDGES;
    #pragma unroll
    for (int i = 0; i < 16; i++) {
        int e = base + i * 256 + tid;
        if (e < N_EDGES) {
            int d = dst[eb + e];
            myd[i] = d; mys[i] = src[eb + e];
            atomicAdd(&cnt[d >> 10], 1);
        } else myd[i] = -1;
    }
    __syncthreads();
    if (tid < 128) incl[tid] = cnt[tid];
    __syncthreads();
    for (int d = 1; d < 128; d <<= 1) {
        int t = 0;
        if (tid < 128 && tid >= d) t = incl[tid - d];
        __syncthreads();
        if (tid < 128 && tid >= d) incl[tid] += t;
        __syncthreads();
    }
    if (tid < 128) {
        wcur[tid] = incl[tid] - cnt[tid];
        gb[tid] = (tid < NB && cnt[tid] > 0) ? atomicAdd(&bcur[r * NB + tid], cnt[tid]) : 0;
    }
    __syncthreads();
    #pragma unroll
    for (int i = 0; i < 16; i++) {
        if (myd[i] >= 0) {
            int bkt = myd[i] >> 10;
            int p = atomicAdd(&wcur[bkt], 1);
            stage[p] = make_uint2((unsigned)myd[i], (unsigned)mys[i]);
        }
    }
    __syncthreads();
    int tot = min(4096, N_EDGES - base);
    for (int i = tid; i < tot; i += 256) {
        uint2 u = stage[i];
        int bkt = (int)(u.x >> 10);
        int ex = incl[bkt] - cnt[bkt];
        ebin[eb + gb[bkt] + (i - ex)] = ((u.x & 1023u) << 17) | u.y;
    }
}

__global__ __launch_bounds__(256) void k_nhist(const unsigned* __restrict__ ebin,
                                               const int* __restrict__ bptr,
                                               int* __restrict__ rowptr) {
    int b = blockIdx.x, r = blockIdx.y, tid = threadIdx.x;
    __shared__ int cnt[1024];
    __shared__ int wsum[4];
    for (int i = tid; i < 1024; i += 256) cnt[i] = 0;
    __syncthreads();
    int es = bptr[r * (NB + 1) + b], ee = bptr[r * (NB + 1) + b + 1];
    size_t eb = (size_t)r * N_EDGES;
    for (int i = es + tid; i < ee; i += 256) atomicAdd(&cnt[(ebin[eb + i] >> 17) & 1023u], 1);
    __syncthreads();
    int b4 = tid * 4;
    int c0 = cnt[b4], c1 = cnt[b4 + 1], c2 = cnt[b4 + 2], c3 = cnt[b4 + 3];
    int ts = c0 + c1 + c2 + c3;
    int lane = tid & 63, wid = tid >> 6;
    int v = ts;
    #pragma unroll
    for (int d = 1; d < 64; d <<= 1) { int t = __shfl_up(v, d); if (lane >= d) v += t; }
    if (lane == 63) wsum[wid] = v;
    __syncthreads();
    int woff = 0;
    for (int w = 0; w < wid; w++) woff += wsum[w];
    int p = woff + v - ts;
    int node0 = b << 10;
    int rp = r * (N_NODES + 1);
    int nd;
    nd = node0 + b4;     if (nd < N_NODES) rowptr[rp + nd] = es + p; p += c0;
    nd = node0 + b4 + 1; if (nd < N_NODES) rowptr[rp + nd] = es + p; p += c1;
    nd = node0 + b4 + 2; if (nd < N_NODES) rowptr[rp + nd] = es + p; p += c2;
    nd = node0 + b4 + 3; if (nd < N_NODES) rowptr[rp + nd] = es + p;
    if (b == NB - 1 && tid == 0) rowptr[rp + N_NODES] = bptr[r * (NB + 1) + NB];
}

__global__ __launch_bounds__(256) void k_scat2(const unsigned* __restrict__ ebin,
                                               const int* __restrict__ bptr,
                                               const int* __restrict__ rowptr,
                                               int* __restrict__ csrc) {
    int b = blockIdx.x, r = blockIdx.y, tid = threadIdx.x;
    __shared__ int cnt[1024];
    __shared__ int rloc[1024];
    __shared__ int stage[8192];
    int node0 = b << 10;
    int rp = r * (N_NODES + 1);
    int rs = rowptr[rp + node0];
    for (int i = tid; i < 1024; i += 256) {
        cnt[i] = 0;
        int nd = node0 + i; if (nd > N_NODES) nd = N_NODES;
        rloc[i] = rowptr[rp + nd] - rs;
    }
    __syncthreads();
    int es = bptr[r * (NB + 1) + b], ee = bptr[r * (NB + 1) + b + 1];
    int sz = ee - es;
    size_t eb = (size_t)r * N_EDGES;
    if (sz <= 8192) {
        for (int i = es + tid; i < ee; i += 256) {
            unsigned u = ebin[eb + i];
            int dl = (int)((u >> 17) & 1023u);
            int rk = atomicAdd(&cnt[dl], 1);
            stage[rloc[dl] + rk] = (int)(u & 0x1FFFFu);
        }
        __syncthreads();
        for (int i = tid; i < sz; i += 256) csrc[eb + rs + i] = stage[i];
    } else {
        for (int i = es + tid; i < ee; i += 256) {
            unsigned u = ebin[eb + i];
            int dl = (int)((u >> 17) & 1023u);
            int rk = atomicAdd(&cnt[dl], 1);
            csrc[eb + rs + rloc[dl] + rk] = (int)(u & 0x1FFFFu);
        }
    }
}

// ---------------- W prep: f32 [k][col] -> bf16 [col][k ^ ((col&7)<<3)] ----------------
__global__ void k_wprep(const float* __restrict__ Ws, short* __restrict__ Wt) {
    int i = blockIdx.x * blockDim.x + threadIdx.x;
    if (i < 6 * 16384) {
        int lr = i >> 14, rem = i & 16383, k = rem >> 7, col = rem & 127;
        Wt[lr * 16384 + col * 128 + (k ^ ((col & 7) << 3))] = f2bf(Ws[i]);
    }
}

// clf_W f32 [128 k][64 col] -> bf16 [col][k ^ ((col&7)<<3)]
__global__ void k_wprep2(const float* __restrict__ Wc, short* __restrict__ Wcb) {
    int i = blockIdx.x * blockDim.x + threadIdx.x;
    if (i < 8192) {
        int k = i >> 6, col = i & 63;
        Wcb[col * 128 + (k ^ ((col & 7) << 3))] = f2bf(Wc[i]);
    }
}

// ---------------- f32 -> bf16 bulk convert ----------------
__global__ void k_cvt(const float* __restrict__ in, short* __restrict__ out, int n) {
    int i = blockIdx.x * blockDim.x + threadIdx.x;
    int stride = gridDim.x * blockDim.x;
    for (int base = i * 8; base < n; base += stride * 8) {
        float4 x = *(const float4*)(in + base);
        float4 y = *(const float4*)(in + base + 4);
        short8v o;
        o[0] = f2bf(x.x); o[1] = f2bf(x.y); o[2] = f2bf(x.z); o[3] = f2bf(x.w);
        o[4] = f2bf(y.x); o[5] = f2bf(y.y); o[6] = f2bf(y.z); o[7] = f2bf(y.w);
        *(short8v*)(out + base) = o;
    }
}

// ---------------- MFMA GEMM over 3 relations in one dispatch: featb[r] bf16 + fused el/er ----------------
__global__ __launch_bounds__(256) void k_gemm3(const short* __restrict__ Abf,
                                               const short* __restrict__ Wt3,    // 3 x 16384, pre-swizzled
                                               const float* __restrict__ al3,    // [3][128]
                                               const float* __restrict__ ar3,    // [3][128]
                                               short* __restrict__ featb,        // [3][N*128]
                                               float4* __restrict__ elr,         // [3][N]
                                               int nrows) {
    __shared__ __align__(16) short Wl[128 * 128];
    int tid = threadIdx.x;
    int lane = tid & 63, wid = tid >> 6;
    int q = lane >> 4, j = lane & 15;
    int rowbase = blockIdx.x * 128 + wid * 32;

    // A fragments once (shared by all 3 relations)
    short8v a[2][4];
    #pragma unroll
    for (int rb = 0; rb < 2; rb++) {
        int row = rowbase + rb * 16 + j;
        const short* ap = Abf + (size_t)row * 128 + q * 8;
        bool ok = row < nrows;
        #pragma unroll
        for (int kk = 0; kk < 4; kk++)
            a[rb][kk] = ok ? *(const short8v*)(ap + kk * 32) : (short8v)0;
    }

    for (int cr = 0; cr < 3; cr++) {
        if (cr) __syncthreads();   // all waves done reading Wl before overwrite
        {
            const float4* srcv = (const float4*)(Wt3 + cr * 16384);
            float4* dstv = (float4*)Wl;
            #pragma unroll
            for (int i = 0; i < 8; i++) dstv[tid + i * 256] = srcv[tid + i * 256];
        }
        float alv[8], arv[8];
        #pragma unroll
        for (int cb = 0; cb < 8; cb++) {
            alv[cb] = al3[cr * 128 + cb * 16 + j];
            arv[cb] = ar3[cr * 128 + cb * 16 + j];
        }
        __syncthreads();

        f32x4 acc[2][8] = {};
        #pragma unroll
        for (int cb = 0; cb < 8; cb++) {
            int col = cb * 16 + j;
            const short* wp = Wl + col * 128;
            int sw = (col & 7) << 3;
            #pragma unroll
            for (int kk = 0; kk < 4; kk++) {
                short8v b = *(const short8v*)(wp + ((kk * 32 + q * 8) ^ sw));
                acc[0][cb] = __builtin_amdgcn_mfma_f32_16x16x32_bf16(a[0][kk], b, acc[0][cb], 0, 0, 0);
                acc[1][cb] = __builtin_amdgcn_mfma_f32_16x16x32_bf16(a[1][kk], b, acc[1][cb], 0, 0, 0);
            }
        }

        short* outB = featb + (size_t)cr * N_NODES * 128;
        #pragma unroll
        for (int rb = 0; rb < 2; rb++) {
            int row0 = rowbase + rb * 16 + q * 4;
            #pragma unroll
            for (int reg = 0; reg < 4; reg++) {
                int row = row0 + reg;
                if (row < nrows) {
                    short* op = outB + (size_t)row * 128 + j;
                    #pragma unroll
                    for (int cb = 0; cb < 8; cb++) op[cb * 16] = f2bf(acc[rb][cb][reg]);
                }
            }
        }

        // fused el/er
        float4* elro = elr + (size_t)cr * N_NODES;
        #pragma unroll
        for (int rb = 0; rb < 2; rb++) {
            float e0[4], e1[4], r0[4], r1[4];
            #pragma unroll
            for (int reg = 0; reg < 4; reg++) {
                float se0 = 0.f, se1 = 0.f, sr0 = 0.f, sr1 = 0.f;
                #pragma unroll
                for (int cb = 0; cb < 4; cb++) {
                    se0 += acc[rb][cb][reg] * alv[cb];
                    sr0 += acc[rb][cb][reg] * arv[cb];
                    se1 += acc[rb][cb + 4][reg] * alv[cb + 4];
                    sr1 += acc[rb][cb + 4][reg] * arv[cb + 4];
                }
                #pragma unroll
                for (int off = 1; off < 16; off <<= 1) {
                    se0 += __shfl_xor(se0, off);
                    se1 += __shfl_xor(se1, off);
                    sr0 += __shfl_xor(sr0, off);
                    sr1 += __shfl_xor(sr1, off);
                }
                e0[reg] = se0; e1[reg] = se1; r0[reg] = sr0; r1[reg] = sr1;
            }
            if (j < 4) {
                int row = rowbase + rb * 16 + q * 4 + j;
                if (row < nrows) {
                    float4 v;
                    v.x = j == 0 ? e0[0] : j == 1 ? e0[1] : j == 2 ? e0[2] : e0[3];
                    v.y = j == 0 ? e1[0] : j == 1 ? e1[1] : j == 2 ? e1[2] : e1[3];
                    v.z = j == 0 ? r0[0] : j == 1 ? r0[1] : j == 2 ? r0[2] : r0[3];
                    v.w = j == 0 ? r1[0] : j == 1 ? r1[1] : j == 2 ? r1[2] : r1[3];
                    elro[row] = v;
                }
            }
        }
    }
}

// ---------------- merged 3-relation softmax + gather-aggregate (wave per dst node) ----------------
// Concatenated lane space: lane l handles the l-th edge of [rel0 edges | rel1 | rel2].
// One elr gather + exp-pair per lane covers all relations; per-relation softmax sums via
// inclusive wave scan + boundary readlanes; alpha pre-scaled into packed bf16 -> main loop is
// relation-blind: readlane(addr), readlane(pk), gather, 2 FMA. Fallback for total degree > 64.
__global__ __launch_bounds__(256) void k_agg3(const short* __restrict__ feat,   // [3][N*128]
                                              const float4* __restrict__ elr,   // [3][N]
                                              const int* __restrict__ rowptr,   // [3][N+1]
                                              const int* __restrict__ csrc,     // [3][E]
                                              const float* __restrict__ bias,   // [3][128]
                                              short* __restrict__ outB, int nrows) {
    int wid = threadIdx.x >> 6, lane = threadIdx.x & 63;
    int v = (blockIdx.x << 2) + wid;
    if (v >= nrows) return;
    int c0 = lane << 1;
    bool lo = lane < 32;

    int beg[3], deg[3];
    #pragma unroll
    for (int r = 0; r < 3; r++) {
        beg[r] = rowptr[r * (N_NODES + 1) + v];
        deg[r] = rowptr[r * (N_NODES + 1) + v + 1] - beg[r];
    }
    float4 ev0 = elr[v];
    float4 ev1 = elr[(size_t)N_NODES + v];
    float4 ev2 = elr[(size_t)2 * N_NODES + v];
    int tc = deg[0] + deg[1] + deg[2];

    float t0 = bias[c0] + bias[128 + c0] + bias[256 + c0];
    float t1 = bias[c0 + 1] + bias[128 + c0 + 1] + bias[256 + c0 + 1];

    if (tc <= 64) {
        int b0 = deg[0], b01 = deg[0] + deg[1];
        int rsel = (lane >= b0 ? 1 : 0) + (lane >= b01 ? 1 : 0);
        int rofs = rsel == 0 ? 0 : (rsel == 1 ? b0 : b01);
        int idx = lane - rofs;
        bool val = lane < tc;
        float evz = rsel == 0 ? ev0.z : (rsel == 1 ? ev1.z : ev2.z);
        float evw = rsel == 0 ? ev0.w : (rsel == 1 ? ev1.w : ev2.w);
        int s = val ? csrc[(size_t)rsel * N_EDGES + beg[rsel] + idx] : 0;
        float4 es = elr[(size_t)rsel * N_NODES + s];
        float e0 = es.x + evz; e0 = e0 >= 0.f ? e0 : NEG_SLOPE * e0;
        float e1 = es.y + evw; e1 = e1 >= 0.f ? e1 : NEG_SLOPE * e1;
        float p0 = val ? __expf(e0) : 0.f;
        float p1 = val ? __expf(e1) : 0.f;

        // inclusive wave scan of (p0, p1)
        float s0 = p0, s1 = p1;
        #pragma unroll
        for (int d = 1; d < 64; d <<= 1) {
            float u0 = __shfl_up(s0, d), u1 = __shfl_up(s1, d);
            if (lane >= d) { s0 += u0; s1 += u1; }
        }
        // per-relation sums from scan boundaries (uniform indices)
        float E00 = (b0 > 0) ? rlf(s0, b0 - 1) : 0.f;
        float E01 = (b01 > b0) ? rlf(s0, b01 - 1) : E00;
        float E02 = (tc > b01) ? rlf(s0, tc - 1) : E01;
        float E10 = (b0 > 0) ? rlf(s1, b0 - 1) : 0.f;
        float E11 = (b01 > b0) ? rlf(s1, b01 - 1) : E10;
        float E12 = (tc > b01) ? rlf(s1, tc - 1) : E11;
        float m00 = E00, m01 = E01 - E00, m02 = E02 - E01;
        float m10 = E10, m11 = E11 - E10, m12 = E12 - E11;
        float i00 = m00 > 0.f ? 1.0f / m00 : 0.f;
        float i01 = m01 > 0.f ? 1.0f / m01 : 0.f;
        float i02 = m02 > 0.f ? 1.0f / m02 : 0.f;
        float i10 = m10 > 0.f ? 1.0f / m10 : 0.f;
        float i11 = m11 > 0.f ? 1.0f / m11 : 0.f;
        float i12 = m12 > 0.f ? 1.0f / m12 : 0.f;
        float iv0 = rsel == 0 ? i00 : (rsel == 1 ? i01 : i02);
        float iv1 = rsel == 0 ? i10 : (rsel == 1 ? i11 : i12);
        unsigned pkl = val ? (((unsigned)(unsigned short)f2bf(p0 * iv0)) |
                              (((unsigned)(unsigned short)f2bf(p1 * iv1)) << 16)) : 0u;
        int addr = (rsel * N_NODES + s) << 7;   // element offset of feat row

        float xa = 0.f, xb = 0.f, ya = 0.f, yb = 0.f;
        for (int j0 = 0; j0 < tc; j0 += 4) {
            int a0_ = __builtin_amdgcn_readlane(addr, j0);
            int a1_ = __builtin_amdgcn_readlane(addr, j0 + 1);
            int a2_ = __builtin_amdgcn_readlane(addr, j0 + 2);
            int a3_ = __builtin_amdgcn_readlane(addr, j0 + 3);
            unsigned b0_ = (unsigned)__builtin_amdgcn_readlane((int)pkl, j0);
            unsigned b1_ = (unsigned)__builtin_amdgcn_readlane((int)pkl, j0 + 1);
            unsigned b2_ = (unsigned)__builtin_amdgcn_readlane((int)pkl, j0 + 2);
            unsigned b3_ = (unsigned)__builtin_amdgcn_readlane((int)pkl, j0 + 3);
            unsigned u0 = *(const unsigned*)(feat + (size_t)(unsigned)a0_ + c0);
            unsigned u1 = *(const unsigned*)(feat + (size_t)(unsigned)a1_ + c0);
            unsigned u2 = *(const unsigned*)(feat + (size_t)(unsigned)a2_ + c0);
            unsigned u3 = *(const unsigned*)(feat + (size_t)(unsigned)a3_ + c0);
            float q0 = asf(lo ? (b0_ << 16) : (b0_ & 0xffff0000u));
            float q1 = asf(lo ? (b1_ << 16) : (b1_ & 0xffff0000u));
            float q2 = asf(lo ? (b2_ << 16) : (b2_ & 0xffff0000u));
            float q3 = asf(lo ? (b3_ << 16) : (b3_ & 0xffff0000u));
            xa += q0 * bflo(u0); xb += q0 * bfhi(u0);
            ya += q1 * bflo(u1); yb += q1 * bfhi(u1);
            xa += q2 * bflo(u2); xb += q2 * bfhi(u2);
            ya += q3 * bflo(u3); yb += q3 * bfhi(u3);
        }
        t0 += xa + ya;
        t1 += xb + yb;
    } else {
        // generic fallback: per-relation, 64-chunked, sum + divide at end
        float evzs[3] = {ev0.z, ev1.z, ev2.z};
        float evws[3] = {ev0.w, ev1.w, ev2.w};
        #pragma unroll
        for (int r = 0; r < 3; r++) {
            const short* fb = feat + (size_t)r * (N_NODES * 128);
            float sp = 0.f, a0 = 0.f, a1 = 0.f;
            int e_end = beg[r] + deg[r];
            for (int base = beg[r]; base < e_end; base += 64) {
                int idx = base + lane;
                bool val = idx < e_end;
                int sv2 = val ? csrc[(size_t)r * N_EDGES + idx] : 0;
                float4 es = elr[(size_t)r * N_NODES + sv2];
                float e0 = es.x + evzs[r]; e0 = e0 >= 0.f ? e0 : NEG_SLOPE * e0;
                float e1 = es.y + evws[r]; e1 = e1 >= 0.f ? e1 : NEG_SLOPE * e1;
                float q0v = val ? __expf(e0) : 0.f;
                float q1v = val ? __expf(e1) : 0.f;
                int bcn = min(64, e_end - base);
                for (int k = 0; k < bcn; k++) {
                    int ss = __builtin_amdgcn_readlane(sv2, k);
                    float q0 = rlf(q0v, k), q1 = rlf(q1v, k);
                    float pp = lo ? q0 : q1;
                    unsigned u = *(const unsigned*)(fb + ((size_t)(unsigned)ss << 7) + c0);
                    sp += pp;
                    a0 += pp * bflo(u);
                    a1 += pp * bfhi(u);
                }
            }
            float inv = sp > 0.f ? 1.0f / sp : 0.f;
            t0 += a0 * inv;
            t1 += a1 * inv;
        }
    }

    unsigned pko = ((unsigned)(unsigned short)f2bf(fmaxf(t0, 0.f))) |
                   (((unsigned)(unsigned short)f2bf(fmaxf(t1, 0.f))) << 16);
    *(unsigned*)(outB + (size_t)v * 128 + c0) = pko;
}

// ---------------- BN stats (bf16 relu'd input, vectorized) ----------------
__global__ __launch_bounds__(256) void k_bnstat(const short* __restrict__ h,
                                                float* __restrict__ sums, int nrows) {
    int tid = threadIdx.x;
    int cg = tid & 15, rgrp = tid >> 4;
    float s[8] = {}, q[8] = {};
    for (int row = blockIdx.x * 16 + rgrp; row < nrows; row += gridDim.x * 16) {
        short8v u = *(const short8v*)(h + (size_t)row * 128 + cg * 8);
        #pragma unroll
        for (int i = 0; i < 8; i++) {
            float x = bfs(u[i]);
            s[i] += x; q[i] += x * x;
        }
    }
    __shared__ float ls[16][128];
    __shared__ float lq[16][128];
    #pragma unroll
    for (int i = 0; i < 8; i++) { ls[rgrp][cg * 8 + i] = s[i]; lq[rgrp][cg * 8 + i] = q[i]; }
    __syncthreads();
    int t = tid;
    if (t < 128) {
        float ts = 0.f, tq = 0.f;
        #pragma unroll
        for (int g = 0; g < 16; g++) { ts += ls[g][t]; tq += lq[g][t]; }
        atomicAdd(&sums[t], ts);
        atomicAdd(&sums[128 + t], tq);
    }
}

// ---------------- classifier: BN-normalize (input pre-relu'd bf16) -> MFMA GEMM [N,128]x[128,64] ----------------
__global__ __launch_bounds__(256) void k_clf(const short* __restrict__ h,
                                             const float* __restrict__ sums,
                                             const float* __restrict__ bn_w,
                                             const float* __restrict__ bn_b,
                                             const short* __restrict__ Wcb,
                                             const float* __restrict__ cbias,
                                             float* __restrict__ out, int nrows) {
    __shared__ __align__(16) short Wl[64 * 128];
    __shared__ float2 bnp[128];
    int tid = threadIdx.x;
    {
        const float4* srcv = (const float4*)Wcb;
        float4* dstv = (float4*)Wl;
        #pragma unroll
        for (int i = 0; i < 4; i++) dstv[tid + i * 256] = srcv[tid + i * 256];
    }
    if (tid < 128) {
        float mu = sums[tid] / (float)nrows;
        float var = sums[128 + tid] / (float)nrows - mu * mu;
        float rs = rsqrtf(var + 1e-5f);
        float sc = bn_w[tid] * rs;
        bnp[tid] = make_float2(sc, bn_b[tid] - mu * sc);
    }
    __syncthreads();

    int lane = tid & 63, wid = tid >> 6;
    int q = lane >> 4, j = lane & 15;
    int rowbase = blockIdx.x * 128 + wid * 32;

    float cbv[4];
    #pragma unroll
    for (int cb = 0; cb < 4; cb++) cbv[cb] = cbias[cb * 16 + j];

    short8v a[2][4];
    #pragma unroll
    for (int rb = 0; rb < 2; rb++) {
        int row = rowbase + rb * 16 + j;
        bool ok = row < nrows;
        const short* hp = h + (size_t)row * 128 + q * 8;
        #pragma unroll
        for (int kk = 0; kk < 4; kk++) {
            short8v u = ok ? *(const short8v*)(hp + kk * 32) : (short8v)0;
            int k0 = kk * 32 + q * 8;
            short8v av;
            #pragma unroll
            for (int i = 0; i < 8; i++) {
                float2 bp = bnp[k0 + i];
                av[i] = f2bf(bfs(u[i]) * bp.x + bp.y);
            }
            a[rb][kk] = av;
        }
    }

    f32x4 acc[2][4] = {};
    #pragma unroll
    for (int cb = 0; cb < 4; cb++) {
        int col = cb * 16 + j;
        const short* wp = Wl + col * 128;
        int sw = (col & 7) << 3;
        #pragma unroll
        for (int kk = 0; kk < 4; kk++) {
            short8v b = *(const short8v*)(wp + ((kk * 32 + q * 8) ^ sw));
            acc[0][cb] = __builtin_amdgcn_mfma_f32_16x16x32_bf16(a[0][kk], b, acc[0][cb], 0, 0, 0);
            acc[1][cb] = __builtin_amdgcn_mfma_f32_16x16x32_bf16(a[1][kk], b, acc[1][cb], 0, 0, 0);
        }
    }

    #pragma unroll
    for (int rb = 0; rb < 2; rb++) {
        int row0 = rowbase + rb * 16 + q * 4;
        #pragma unroll
        for (int reg = 0; reg < 4; reg++) {
            int row = row0 + reg;
            if (row < nrows) {
                float* op = out + (size_t)row * 64 + j;
                #pragma unroll
                for (int cb = 0; cb < 4; cb++) op[cb * 16] = acc[rb][cb][reg] + cbv[cb];
            }
        }
    }
}

// ---------------- launch ----------------

extern "C" void kernel_launch(void* const* d_in, const int* in_sizes, int n_in,
                              void* d_out, int out_size, void* d_ws, size_t ws_size,
                              hipStream_t stream) {
    (void)in_sizes; (void)n_in; (void)out_size; (void)ws_size;
    const float* feat_in = (const float*)d_in[0];
    const float* Ws      = (const float*)d_in[1];
    const float* als     = (const float*)d_in[2];
    const float* ars     = (const float*)d_in[3];
    const float* bs      = (const float*)d_in[4];
    const float* bn_w    = (const float*)d_in[5];
    const float* bn_b    = (const float*)d_in[6];
    const float* clf_W   = (const float*)d_in[7];
    const float* clf_b   = (const float*)d_in[8];
    const int*   src     = (const int*)d_in[9];
    const int*   dst     = (const int*)d_in[10];
    float* out = (float*)d_out;

    const int N = N_NODES, E = N_EDGES;
    char* p = (char*)d_ws;
    auto carve = [&](size_t bytes) { char* q = p; p += (bytes + 255) & ~255ULL; return q; };
    int*      bcnt   = (int*)carve((size_t)3 * NB * 4);
    int*      bptr   = (int*)carve((size_t)3 * (NB + 1) * 4);
    int*      bcur   = (int*)carve((size_t)3 * NB * 4);
    int*      rowptr = (int*)carve((size_t)3 * (N + 1) * 4);
    int*      csrc   = (int*)carve((size_t)3 * E * 4);
    unsigned* ebin   = (unsigned*)carve((size_t)3 * E * 4);
    float4*   elr    = (float4*)carve((size_t)3 * N * 16);
    float*    bnsum  = (float*)carve(256 * 4);
    short*    Wtg    = (short*)carve((size_t)6 * 16384 * 2);
    short*    Wcb    = (short*)carve((size_t)8192 * 2);
    short*    hA     = (short*)carve((size_t)N * 128 * 2);
    short*    hB     = (short*)carve((size_t)N * 128 * 2);
    short*    featb  = (short*)carve((size_t)3 * N * 128 * 2);

    // weight prep + input conversion
    k_wprep<<<(6 * 16384 + 255) / 256, 256, 0, stream>>>(Ws, Wtg);
    k_wprep2<<<32, 256, 0, stream>>>(clf_W, Wcb);
    k_cvt<<<2048, 256, 0, stream>>>(feat_in, hA, N * 128);

    // CSR build via binned sort
    hipMemsetAsync(bcnt, 0, (size_t)3 * NB * 4, stream);
    dim3 gchunk((E + 4095) / 4096, 3);
    k_bhist<<<gchunk, 256, 0, stream>>>(dst, bcnt);
    k_bscan<<<3, 64, 0, stream>>>(bcnt, bptr, bcur);
    k_bin<<<gchunk, 256, 0, stream>>>(src, dst, bcur, ebin);
    dim3 gbkt(NB, 3);
    k_nhist<<<gbkt, 256, 0, stream>>>(ebin, bptr, rowptr);
    k_scat2<<<gbkt, 256, 0, stream>>>(ebin, bptr, rowptr, csrc);

    int gq = (N + 3) / 4;
    for (int l = 0; l < 2; l++) {
        const short* hin = (l == 0) ? hA : hB;
        short* hout = (l == 0) ? hB : hA;
        k_gemm3<<<(N + 127) / 128, 256, 0, stream>>>(hin, Wtg + (size_t)l * 3 * 16384,
                                                     als + (size_t)l * 384, ars + (size_t)l * 384,
                                                     featb, elr, N);
        k_agg3<<<gq, 256, 0, stream>>>(featb, elr, rowptr, csrc,
                                       bs + (size_t)l * 384, hout, N);
    }

    // BN + classifier on hA (layer-2 output, relu'd bf16)
    hipMemsetAsync(bnsum, 0, 256 * 4, stream);
    k_bnstat<<<512, 256, 0, stream>>>(hA, bnsum, N);
    k_clf<<<(N + 127) / 128, 256, 0, stream>>>(hA, bnsum, bn_w, bn_b, Wcb, clf_b, out, N);
}

// Round 14
// 354.059 us; speedup vs baseline: 1.1148x; 1.0026x over previous
//
#include <hip/hip_runtime.h>
#include <hip/hip_bf16.h>

#define N_NODES 100000
#define N_EDGES 500000
#define HID 128
#define NEG_SLOPE 0.2f
#define NB 98           // buckets of 1024 nodes: ceil(100000/1024)

typedef __attribute__((ext_vector_type(8))) short short8v;
typedef __attribute__((ext_vector_type(4))) short short4v;
typedef __attribute__((ext_vector_type(4))) float f32x4;

__device__ __forceinline__ short f2bf(float x) {
    union { float f; unsigned u; } v; v.f = x;
    unsigned r = v.u + 0x7fff + ((v.u >> 16) & 1);  // RNE
    return (short)(r >> 16);
}
__device__ __forceinline__ float bflo(unsigned u) {
    union { unsigned x; float f; } c; c.x = u << 16; return c.f;
}
__device__ __forceinline__ float bfhi(unsigned u) {
    union { unsigned x; float f; } c; c.x = u & 0xffff0000u; return c.f;
}
__device__ __forceinline__ float bfs(short s) {
    union { unsigned x; float f; } c; c.x = ((unsigned)(unsigned short)s) << 16; return c.f;
}
__device__ __forceinline__ float asf(unsigned u) {
    union { unsigned x; float f; } c; c.x = u; return c.f;
}
__device__ __forceinline__ float rlf(float x, int i) {
    return asf((unsigned)__builtin_amdgcn_readlane((int)__float_as_uint(x), i));
}

// ---------------- CSR build: binned two-level sort ----------------

__global__ __launch_bounds__(256) void k_bhist(const int* __restrict__ dst, int* __restrict__ bcnt) {
    int r = blockIdx.y, tid = threadIdx.x;
    int base = blockIdx.x * 4096;
    __shared__ int h[128];
    if (tid < 128) h[tid] = 0;
    __syncthreads();
    size_t eb = (size_t)r * N_EDGES;
    int lim = min(base + 4096, N_EDGES);
    for (int e = base + tid; e < lim; e += 256) atomicAdd(&h[dst[eb + e] >> 10], 1);
    __syncthreads();
    if (tid < NB && h[tid]) atomicAdd(&bcnt[r * NB + tid], h[tid]);
}

__global__ void k_bscan(const int* __restrict__ bcnt, int* __restrict__ bptr, int* __restrict__ bcur) {
    int r = blockIdx.x, lane = threadIdx.x;
    int carry = 0;
    for (int base = 0; base < NB; base += 64) {
        int i = base + lane;
        int c = (i < NB) ? bcnt[r * NB + i] : 0;
        int v = c;
        #pragma unroll
        for (int d = 1; d < 64; d <<= 1) { int t = __shfl_up(v, d); if (lane >= d) v += t; }
        int excl = carry + v - c;
        if (i < NB) { bptr[r * (NB + 1) + i] = excl; bcur[r * NB + i] = excl; }
        carry += __shfl(v, 63);
    }
    if (lane == 0) bptr[r * (NB + 1) + NB] = carry;
}

// bin edges into bucket regions of ebin packed as ((dst&1023)<<17 | src)
__global__ __launch_bounds__(256) void k_bin(const int* __restrict__ src, const int* __restrict__ dst,
                                             int* __restrict__ bcur, unsigned* __restrict__ ebin) {
    int r = blockIdx.y, tid = threadIdx.x;
    int base = blockIdx.x * 4096;
    __shared__ int cnt[128], incl[128], gb[128], wcur[128];
    __shared__ uint2 stage[4096];
    if (tid < 128) cnt[tid] = 0;
    __syncthreads();
    int myd[16], mys[16];
    size_t eb = (size_t)r * N_EDGES;
    #pragma unroll
    for (int i = 0; i < 16; i++) {
        int e = base + i * 256 + tid;
        if (e < N_EDGES) {
            int d = dst[eb + e];
            myd[i] = d; mys[i] = src[eb + e];
            atomicAdd(&cnt[d >> 10], 1);
        } else myd[i] = -1;
    }
    __syncthreads();
    if (tid < 128) incl[tid] = cnt[tid];
    __syncthreads();
    for (int d = 1; d < 128; d <<= 1) {
        int t = 0;
        if (tid < 128 && tid >= d) t = incl[tid - d];
        __syncthreads();
        if (tid < 128 && tid >= d) incl[tid] += t;
        __syncthreads();
    }
    if (tid < 128) {
        wcur[tid] = incl[tid] - cnt[tid];
        gb[tid] = (tid < NB && cnt[tid] > 0) ? atomicAdd(&bcur[r * NB + tid], cnt[tid]) : 0;
    }
    __syncthreads();
    #pragma unroll
    for (int i = 0; i < 16; i++) {
        if (myd[i] >= 0) {
            int bkt = myd[i] >> 10;
            int p = atomicAdd(&wcur[bkt], 1);
            stage[p] = make_uint2((unsigned)myd[i], (unsigned)mys[i]);
        }
    }
    __syncthreads();
    int tot = min(4096, N_EDGES - base);
    for (int i = tid; i < tot; i += 256) {
        uint2 u = stage[i];
        int bkt = (int)(u.x >> 10);
        int ex = incl[bkt] - cnt[bkt];
        ebin[eb + gb[bkt] + (i - ex)] = ((u.x & 1023u) << 17) | u.y;
    }
}

__global__ __launch_bounds__(256) void k_nhist(const unsigned* __restrict__ ebin,
                                               const int* __restrict__ bptr,
                                               int* __restrict__ rowptr) {
    int b = blockIdx.x, r = blockIdx.y, tid = threadIdx.x;
    __shared__ int cnt[1024];
    __shared__ int wsum[4];
    for (int i = tid; i < 1024; i += 256) cnt[i] = 0;
    __syncthreads();
    int es = bptr[r * (NB + 1) + b], ee = bptr[r * (NB + 1) + b + 1];
    size_t eb = (size_t)r * N_EDGES;
    for (int i = es + tid; i < ee; i += 256) atomicAdd(&cnt[(ebin[eb + i] >> 17) & 1023u], 1);
    __syncthreads();
    int b4 = tid * 4;
    int c0 = cnt[b4], c1 = cnt[b4 + 1], c2 = cnt[b4 + 2], c3 = cnt[b4 + 3];
    int ts = c0 + c1 + c2 + c3;
    int lane = tid & 63, wid = tid >> 6;
    int v = ts;
    #pragma unroll
    for (int d = 1; d < 64; d <<= 1) { int t = __shfl_up(v, d); if (lane >= d) v += t; }
    if (lane == 63) wsum[wid] = v;
    __syncthreads();
    int woff = 0;
    for (int w = 0; w < wid; w++) woff += wsum[w];
    int p = woff + v - ts;
    int node0 = b << 10;
    int rp = r * (N_NODES + 1);
    int nd;
    nd = node0 + b4;     if (nd < N_NODES) rowptr[rp + nd] = es + p; p += c0;
    nd = node0 + b4 + 1; if (nd < N_NODES) rowptr[rp + nd] = es + p; p += c1;
    nd = node0 + b4 + 2; if (nd < N_NODES) rowptr[rp + nd] = es + p; p += c2;
    nd = node0 + b4 + 3; if (nd < N_NODES) rowptr[rp + nd] = es + p;
    if (b == NB - 1 && tid == 0) rowptr[rp + N_NODES] = bptr[r * (NB + 1) + NB];
}

__global__ __launch_bounds__(256) void k_scat2(const unsigned* __restrict__ ebin,
                                               const int* __restrict__ bptr,
                                               const int* __restrict__ rowptr,
                                               int* __restrict__ csrc) {
    int b = blockIdx.x, r = blockIdx.y, tid = threadIdx.x;
    __shared__ int cnt[1024];
    __shared__ int rloc[1024];
    __shared__ int stage[8192];
    int node0 = b << 10;
    int rp = r * (N_NODES + 1);
    int rs = rowptr[rp + node0];
    for (int i = tid; i < 1024; i += 256) {
        cnt[i] = 0;
        int nd = node0 + i; if (nd > N_NODES) nd = N_NODES;
        rloc[i] = rowptr[rp + nd] - rs;
    }
    __syncthreads();
    int es = bptr[r * (NB + 1) + b], ee = bptr[r * (NB + 1) + b + 1];
    int sz = ee - es;
    size_t eb = (size_t)r * N_EDGES;
    if (sz <= 8192) {
        for (int i = es + tid; i < ee; i += 256) {
            unsigned u = ebin[eb + i];
            int dl = (int)((u >> 17) & 1023u);
            int rk = atomicAdd(&cnt[dl], 1);
            stage[rloc[dl] + rk] = (int)(u & 0x1FFFFu);
        }
        __syncthreads();
        for (int i = tid; i < sz; i += 256) csrc[eb + rs + i] = stage[i];
    } else {
        for (int i = es + tid; i < ee; i += 256) {
            unsigned u = ebin[eb + i];
            int dl = (int)((u >> 17) & 1023u);
            int rk = atomicAdd(&cnt[dl], 1);
            csrc[eb + rs + rloc[dl] + rk] = (int)(u & 0x1FFFFu);
        }
    }
}

// ---------------- W prep: f32 [k][col] -> bf16 [col][k ^ ((col&7)<<3)] ----------------
__global__ void k_wprep(const float* __restrict__ Ws, short* __restrict__ Wt) {
    int i = blockIdx.x * blockDim.x + threadIdx.x;
    if (i < 6 * 16384) {
        int lr = i >> 14, rem = i & 16383, k = rem >> 7, col = rem & 127;
        Wt[lr * 16384 + col * 128 + (k ^ ((col & 7) << 3))] = f2bf(Ws[i]);
    }
}

// clf_W f32 [128 k][64 col] -> bf16 [col][k ^ ((col&7)<<3)]; also bias sums per layer
__global__ void k_wprep2(const float* __restrict__ Wc, const float* __restrict__ bs,
                         short* __restrict__ Wcb, float* __restrict__ bsum) {
    int i = blockIdx.x * blockDim.x + threadIdx.x;
    if (i < 8192) {
        int k = i >> 6, col = i & 63;
        Wcb[col * 128 + (k ^ ((col & 7) << 3))] = f2bf(Wc[i]);
    } else if (i < 8192 + 256) {
        int j = i - 8192;
        int l = j >> 7, c = j & 127;
        bsum[j] = bs[(l * 3 + 0) * 128 + c] + bs[(l * 3 + 1) * 128 + c] + bs[(l * 3 + 2) * 128 + c];
    }
}

// ---------------- f32 -> bf16 bulk convert ----------------
__global__ void k_cvt(const float* __restrict__ in, short* __restrict__ out, int n) {
    int i = blockIdx.x * blockDim.x + threadIdx.x;
    int stride = gridDim.x * blockDim.x;
    for (int base = i * 8; base < n; base += stride * 8) {
        float4 x = *(const float4*)(in + base);
        float4 y = *(const float4*)(in + base + 4);
        short8v o;
        o[0] = f2bf(x.x); o[1] = f2bf(x.y); o[2] = f2bf(x.z); o[3] = f2bf(x.w);
        o[4] = f2bf(y.x); o[5] = f2bf(y.y); o[6] = f2bf(y.z); o[7] = f2bf(y.w);
        *(short8v*)(out + base) = o;
    }
}

// ---------------- MFMA GEMM over 3 relations in one dispatch: featb[r] bf16 + fused el/er ----------------
__global__ __launch_bounds__(256) void k_gemm3(const short* __restrict__ Abf,
                                               const short* __restrict__ Wt3,    // 3 x 16384, pre-swizzled
                                               const float* __restrict__ al3,    // [3][128]
                                               const float* __restrict__ ar3,    // [3][128]
                                               short* __restrict__ featb,        // [3][N*128]
                                               float4* __restrict__ elr,         // [3][N]
                                               int nrows) {
    __shared__ __align__(16) short Wl[128 * 128];
    int tid = threadIdx.x;
    int lane = tid & 63, wid = tid >> 6;
    int q = lane >> 4, j = lane & 15;
    int rowbase = blockIdx.x * 128 + wid * 32;

    // A fragments once (shared by all 3 relations)
    short8v a[2][4];
    #pragma unroll
    for (int rb = 0; rb < 2; rb++) {
        int row = rowbase + rb * 16 + j;
        const short* ap = Abf + (size_t)row * 128 + q * 8;
        bool ok = row < nrows;
        #pragma unroll
        for (int kk = 0; kk < 4; kk++)
            a[rb][kk] = ok ? *(const short8v*)(ap + kk * 32) : (short8v)0;
    }

    for (int cr = 0; cr < 3; cr++) {
        if (cr) __syncthreads();   // all waves done reading Wl before overwrite
        {
            const float4* srcv = (const float4*)(Wt3 + cr * 16384);
            float4* dstv = (float4*)Wl;
            #pragma unroll
            for (int i = 0; i < 8; i++) dstv[tid + i * 256] = srcv[tid + i * 256];
        }
        float alv[8], arv[8];
        #pragma unroll
        for (int cb = 0; cb < 8; cb++) {
            alv[cb] = al3[cr * 128 + cb * 16 + j];
            arv[cb] = ar3[cr * 128 + cb * 16 + j];
        }
        __syncthreads();

        f32x4 acc[2][8] = {};
        #pragma unroll
        for (int cb = 0; cb < 8; cb++) {
            int col = cb * 16 + j;
            const short* wp = Wl + col * 128;
            int sw = (col & 7) << 3;
            #pragma unroll
            for (int kk = 0; kk < 4; kk++) {
                short8v b = *(const short8v*)(wp + ((kk * 32 + q * 8) ^ sw));
                acc[0][cb] = __builtin_amdgcn_mfma_f32_16x16x32_bf16(a[0][kk], b, acc[0][cb], 0, 0, 0);
                acc[1][cb] = __builtin_amdgcn_mfma_f32_16x16x32_bf16(a[1][kk], b, acc[1][cb], 0, 0, 0);
            }
        }

        short* outB = featb + (size_t)cr * N_NODES * 128;
        #pragma unroll
        for (int rb = 0; rb < 2; rb++) {
            int row0 = rowbase + rb * 16 + q * 4;
            #pragma unroll
            for (int reg = 0; reg < 4; reg++) {
                int row = row0 + reg;
                if (row < nrows) {
                    short* op = outB + (size_t)row * 128 + j;
                    #pragma unroll
                    for (int cb = 0; cb < 8; cb++) op[cb * 16] = f2bf(acc[rb][cb][reg]);
                }
            }
        }

        // fused el/er
        float4* elro = elr + (size_t)cr * N_NODES;
        #pragma unroll
        for (int rb = 0; rb < 2; rb++) {
            float e0[4], e1[4], r0[4], r1[4];
            #pragma unroll
            for (int reg = 0; reg < 4; reg++) {
                float se0 = 0.f, se1 = 0.f, sr0 = 0.f, sr1 = 0.f;
                #pragma unroll
                for (int cb = 0; cb < 4; cb++) {
                    se0 += acc[rb][cb][reg] * alv[cb];
                    sr0 += acc[rb][cb][reg] * arv[cb];
                    se1 += acc[rb][cb + 4][reg] * alv[cb + 4];
                    sr1 += acc[rb][cb + 4][reg] * arv[cb + 4];
                }
                #pragma unroll
                for (int off = 1; off < 16; off <<= 1) {
                    se0 += __shfl_xor(se0, off);
                    se1 += __shfl_xor(se1, off);
                    sr0 += __shfl_xor(sr0, off);
                    sr1 += __shfl_xor(sr1, off);
                }
                e0[reg] = se0; e1[reg] = se1; r0[reg] = sr0; r1[reg] = sr1;
            }
            if (j < 4) {
                int row = rowbase + rb * 16 + q * 4 + j;
                if (row < nrows) {
                    float4 v;
                    v.x = j == 0 ? e0[0] : j == 1 ? e0[1] : j == 2 ? e0[2] : e0[3];
                    v.y = j == 0 ? e1[0] : j == 1 ? e1[1] : j == 2 ? e1[2] : e1[3];
                    v.z = j == 0 ? r0[0] : j == 1 ? r0[1] : j == 2 ? r0[2] : r0[3];
                    v.w = j == 0 ? r1[0] : j == 1 ? r1[1] : j == 2 ? r1[2] : r1[3];
                    elro[row] = v;
                }
            }
        }
    }
}

// ---------------- merged 3-relation softmax + gather-aggregate (wave per dst node) ----------------
// Concatenated lane space + scan-based per-relation softmax + prescaled packed alpha.
// Main loop per edge: 2 readlane, 1 v_perm (alpha select+f32-ify), 1 lshl, 1 and, 2 fmac.
__global__ __launch_bounds__(256) void k_agg3(const short* __restrict__ feat,   // [3][N*128]
                                              const float4* __restrict__ elr,   // [3][N]
                                              const int* __restrict__ rowptr,   // [3][N+1]
                                              const int* __restrict__ csrc,     // [3][E]
                                              const float* __restrict__ bsum,   // [128] summed bias
                                              short* __restrict__ outB, int nrows) {
    int wid = threadIdx.x >> 6, lane = threadIdx.x & 63;
    int v = (blockIdx.x << 2) + wid;
    if (v >= nrows) return;
    int c0 = lane << 1;
    bool lo = lane < 32;
    unsigned psel = lo ? 0x01000404u : 0x03020404u;   // dest=[0,0,bk,bk+1] from s1 bytes

    int beg[3], deg[3];
    #pragma unroll
    for (int r = 0; r < 3; r++) {
        beg[r] = rowptr[r * (N_NODES + 1) + v];
        deg[r] = rowptr[r * (N_NODES + 1) + v + 1] - beg[r];
    }
    float4 ev0 = elr[v];
    float4 ev1 = elr[(size_t)N_NODES + v];
    float4 ev2 = elr[(size_t)2 * N_NODES + v];
    int tc = deg[0] + deg[1] + deg[2];

    float2 bv = *(const float2*)(bsum + c0);
    float t0 = bv.x, t1 = bv.y;

    if (tc <= 64) {
        int b0 = deg[0], b01 = deg[0] + deg[1];
        int rsel = (lane >= b0 ? 1 : 0) + (lane >= b01 ? 1 : 0);
        int rofs = rsel == 0 ? 0 : (rsel == 1 ? b0 : b01);
        int idx = lane - rofs;
        bool val = lane < tc;
        float evz = rsel == 0 ? ev0.z : (rsel == 1 ? ev1.z : ev2.z);
        float evw = rsel == 0 ? ev0.w : (rsel == 1 ? ev1.w : ev2.w);
        int s = val ? csrc[(size_t)rsel * N_EDGES + beg[rsel] + idx] : 0;
        float4 es = elr[(size_t)rsel * N_NODES + s];
        float e0 = es.x + evz; e0 = e0 >= 0.f ? e0 : NEG_SLOPE * e0;
        float e1 = es.y + evw; e1 = e1 >= 0.f ? e1 : NEG_SLOPE * e1;
        float p0 = val ? __expf(e0) : 0.f;
        float p1 = val ? __expf(e1) : 0.f;

        // inclusive wave scan of (p0, p1)
        float s0 = p0, s1 = p1;
        #pragma unroll
        for (int d = 1; d < 64; d <<= 1) {
            float u0 = __shfl_up(s0, d), u1 = __shfl_up(s1, d);
            if (lane >= d) { s0 += u0; s1 += u1; }
        }
        // per-relation sums from scan boundaries (uniform indices)
        float E00 = (b0 > 0) ? rlf(s0, b0 - 1) : 0.f;
        float E01 = (b01 > b0) ? rlf(s0, b01 - 1) : E00;
        float E02 = (tc > b01) ? rlf(s0, tc - 1) : E01;
        float E10 = (b0 > 0) ? rlf(s1, b0 - 1) : 0.f;
        float E11 = (b01 > b0) ? rlf(s1, b01 - 1) : E10;
        float E12 = (tc > b01) ? rlf(s1, tc - 1) : E11;
        float m00 = E00, m01 = E01 - E00, m02 = E02 - E01;
        float m10 = E10, m11 = E11 - E10, m12 = E12 - E11;
        float i00 = m00 > 0.f ? 1.0f / m00 : 0.f;
        float i01 = m01 > 0.f ? 1.0f / m01 : 0.f;
        float i02 = m02 > 0.f ? 1.0f / m02 : 0.f;
        float i10 = m10 > 0.f ? 1.0f / m10 : 0.f;
        float i11 = m11 > 0.f ? 1.0f / m11 : 0.f;
        float i12 = m12 > 0.f ? 1.0f / m12 : 0.f;
        float iv0 = rsel == 0 ? i00 : (rsel == 1 ? i01 : i02);
        float iv1 = rsel == 0 ? i10 : (rsel == 1 ? i11 : i12);
        unsigned pkl = val ? (((unsigned)(unsigned short)f2bf(p0 * iv0)) |
                              (((unsigned)(unsigned short)f2bf(p1 * iv1)) << 16)) : 0u;
        int addr = (rsel * N_NODES + s) << 7;   // element offset of feat row

        float xa = 0.f, xb = 0.f, ya = 0.f, yb = 0.f;
        for (int j0 = 0; j0 < tc; j0 += 4) {
            int a0_ = __builtin_amdgcn_readlane(addr, j0);
            int a1_ = __builtin_amdgcn_readlane(addr, j0 + 1);
            int a2_ = __builtin_amdgcn_readlane(addr, j0 + 2);
            int a3_ = __builtin_amdgcn_readlane(addr, j0 + 3);
            unsigned b0_ = (unsigned)__builtin_amdgcn_readlane((int)pkl, j0);
            unsigned b1_ = (unsigned)__builtin_amdgcn_readlane((int)pkl, j0 + 1);
            unsigned b2_ = (unsigned)__builtin_amdgcn_readlane((int)pkl, j0 + 2);
            unsigned b3_ = (unsigned)__builtin_amdgcn_readlane((int)pkl, j0 + 3);
            unsigned u0 = *(const unsigned*)(feat + (size_t)(unsigned)a0_ + c0);
            unsigned u1 = *(const unsigned*)(feat + (size_t)(unsigned)a1_ + c0);
            unsigned u2 = *(const unsigned*)(feat + (size_t)(unsigned)a2_ + c0);
            unsigned u3 = *(const unsigned*)(feat + (size_t)(unsigned)a3_ + c0);
            float q0 = asf(__builtin_amdgcn_perm(0u, b0_, psel));
            float q1 = asf(__builtin_amdgcn_perm(0u, b1_, psel));
            float q2 = asf(__builtin_amdgcn_perm(0u, b2_, psel));
            float q3 = asf(__builtin_amdgcn_perm(0u, b3_, psel));
            xa += q0 * bflo(u0); xb += q0 * bfhi(u0);
            ya += q1 * bflo(u1); yb += q1 * bfhi(u1);
            xa += q2 * bflo(u2); xb += q2 * bfhi(u2);
            ya += q3 * bflo(u3); yb += q3 * bfhi(u3);
        }
        t0 += xa + ya;
        t1 += xb + yb;
    } else {
        // generic fallback: per-relation, 64-chunked, sum + divide at end
        float evzs[3] = {ev0.z, ev1.z, ev2.z};
        float evws[3] = {ev0.w, ev1.w, ev2.w};
        #pragma unroll
        for (int r = 0; r < 3; r++) {
            const short* fb = feat + (size_t)r * (N_NODES * 128);
            float sp = 0.f, a0 = 0.f, a1 = 0.f;
            int e_end = beg[r] + deg[r];
            for (int base = beg[r]; base < e_end; base += 64) {
                int idx = base + lane;
                bool val = idx < e_end;
                int sv2 = val ? csrc[(size_t)r * N_EDGES + idx] : 0;
                float4 es = elr[(size_t)r * N_NODES + sv2];
                float e0 = es.x + evzs[r]; e0 = e0 >= 0.f ? e0 : NEG_SLOPE * e0;
                float e1 = es.y + evws[r]; e1 = e1 >= 0.f ? e1 : NEG_SLOPE * e1;
                float q0v = val ? __expf(e0) : 0.f;
                float q1v = val ? __expf(e1) : 0.f;
                int bcn = min(64, e_end - base);
                for (int k = 0; k < bcn; k++) {
                    int ss = __builtin_amdgcn_readlane(sv2, k);
                    float q0 = rlf(q0v, k), q1 = rlf(q1v, k);
                    float pp = lo ? q0 : q1;
                    unsigned u = *(const unsigned*)(fb + ((size_t)(unsigned)ss << 7) + c0);
                    sp += pp;
                    a0 += pp * bflo(u);
                    a1 += pp * bfhi(u);
                }
            }
            float inv = sp > 0.f ? 1.0f / sp : 0.f;
            t0 += a0 * inv;
            t1 += a1 * inv;
        }
    }

    unsigned pko = ((unsigned)(unsigned short)f2bf(fmaxf(t0, 0.f))) |
                   (((unsigned)(unsigned short)f2bf(fmaxf(t1, 0.f))) << 16);
    *(unsigned*)(outB + (size_t)v * 128 + c0) = pko;
}

// ---------------- BN stats (bf16 relu'd input, vectorized) ----------------
__global__ __launch_bounds__(256) void k_bnstat(const short* __restrict__ h,
                                                float* __restrict__ sums, int nrows) {
    int tid = threadIdx.x;
    int cg = tid & 15, rgrp = tid >> 4;
    float s[8] = {}, q[8] = {};
    for (int row = blockIdx.x * 16 + rgrp; row < nrows; row += gridDim.x * 16) {
        short8v u = *(const short8v*)(h + (size_t)row * 128 + cg * 8);
        #pragma unroll
        for (int i = 0; i < 8; i++) {
            float x = bfs(u[i]);
            s[i] += x; q[i] += x * x;
        }
    }
    __shared__ float ls[16][128];
    __shared__ float lq[16][128];
    #pragma unroll
    for (int i = 0; i < 8; i++) { ls[rgrp][cg * 8 + i] = s[i]; lq[rgrp][cg * 8 + i] = q[i]; }
    __syncthreads();
    int t = tid;
    if (t < 128) {
        float ts = 0.f, tq = 0.f;
        #pragma unroll
        for (int g = 0; g < 16; g++) { ts += ls[g][t]; tq += lq[g][t]; }
        atomicAdd(&sums[t], ts);
        atomicAdd(&sums[128 + t], tq);
    }
}

// ---------------- classifier: BN-normalize (input pre-relu'd bf16) -> MFMA GEMM [N,128]x[128,64] ----------------
__global__ __launch_bounds__(256) void k_clf(const short* __restrict__ h,
                                             const float* __restrict__ sums,
                                             const float* __restrict__ bn_w,
                                             const float* __restrict__ bn_b,
                                             const short* __restrict__ Wcb,
                                             const float* __restrict__ cbias,
                                             float* __restrict__ out, int nrows) {
    __shared__ __align__(16) short Wl[64 * 128];
    __shared__ float2 bnp[128];
    int tid = threadIdx.x;
    {
        const float4* srcv = (const float4*)Wcb;
        float4* dstv = (float4*)Wl;
        #pragma unroll
        for (int i = 0; i < 4; i++) dstv[tid + i * 256] = srcv[tid + i * 256];
    }
    if (tid < 128) {
        float mu = sums[tid] / (float)nrows;
        float var = sums[128 + tid] / (float)nrows - mu * mu;
        float rs = rsqrtf(var + 1e-5f);
        float sc = bn_w[tid] * rs;
        bnp[tid] = make_float2(sc, bn_b[tid] - mu * sc);
    }
    __syncthreads();

    int lane = tid & 63, wid = tid >> 6;
    int q = lane >> 4, j = lane & 15;
    int rowbase = blockIdx.x * 128 + wid * 32;

    float cbv[4];
    #pragma unroll
    for (int cb = 0; cb < 4; cb++) cbv[cb] = cbias[cb * 16 + j];

    short8v a[2][4];
    #pragma unroll
    for (int rb = 0; rb < 2; rb++) {
        int row = rowbase + rb * 16 + j;
        bool ok = row < nrows;
        const short* hp = h + (size_t)row * 128 + q * 8;
        #pragma unroll
        for (int kk = 0; kk < 4; kk++) {
            short8v u = ok ? *(const short8v*)(hp + kk * 32) : (short8v)0;
            int k0 = kk * 32 + q * 8;
            short8v av;
            #pragma unroll
            for (int i = 0; i < 8; i++) {
                float2 bp = bnp[k0 + i];
                av[i] = f2bf(bfs(u[i]) * bp.x + bp.y);
            }
            a[rb][kk] = av;
        }
    }

    f32x4 acc[2][4] = {};
    #pragma unroll
    for (int cb = 0; cb < 4; cb++) {
        int col = cb * 16 + j;
        const short* wp = Wl + col * 128;
        int sw = (col & 7) << 3;
        #pragma unroll
        for (int kk = 0; kk < 4; kk++) {
            short8v b = *(const short8v*)(wp + ((kk * 32 + q * 8) ^ sw));
            acc[0][cb] = __builtin_amdgcn_mfma_f32_16x16x32_bf16(a[0][kk], b, acc[0][cb], 0, 0, 0);
            acc[1][cb] = __builtin_amdgcn_mfma_f32_16x16x32_bf16(a[1][kk], b, acc[1][cb], 0, 0, 0);
        }
    }

    #pragma unroll
    for (int rb = 0; rb < 2; rb++) {
        int row0 = rowbase + rb * 16 + q * 4;
        #pragma unroll
        for (int reg = 0; reg < 4; reg++) {
            int row = row0 + reg;
            if (row < nrows) {
                float* op = out + (size_t)row * 64 + j;
                #pragma unroll
                for (int cb = 0; cb < 4; cb++) op[cb * 16] = acc[rb][cb][reg] + cbv[cb];
            }
        }
    }
}

// ---------------- launch ----------------

extern "C" void kernel_launch(void* const* d_in, const int* in_sizes, int n_in,
                              void* d_out, int out_size, void* d_ws, size_t ws_size,
                              hipStream_t stream) {
    (void)in_sizes; (void)n_in; (void)out_size; (void)ws_size;
    const float* feat_in = (const float*)d_in[0];
    const float* Ws      = (const float*)d_in[1];
    const float* als     = (const float*)d_in[2];
    const float* ars     = (const float*)d_in[3];
    const float* bs      = (const float*)d_in[4];
    const float* bn_w    = (const float*)d_in[5];
    const float* bn_b    = (const float*)d_in[6];
    const float* clf_W   = (const float*)d_in[7];
    const float* clf_b   = (const float*)d_in[8];
    const int*   src     = (const int*)d_in[9];
    const int*   dst     = (const int*)d_in[10];
    float* out = (float*)d_out;

    const int N = N_NODES, E = N_EDGES;
    char* p = (char*)d_ws;
    auto carve = [&](size_t bytes) { char* q = p; p += (bytes + 255) & ~255ULL; return q; };
    int*      bcnt   = (int*)carve((size_t)3 * NB * 4);
    int*      bptr   = (int*)carve((size_t)3 * (NB + 1) * 4);
    int*      bcur   = (int*)carve((size_t)3 * NB * 4);
    int*      rowptr = (int*)carve((size_t)3 * (N + 1) * 4);
    int*      csrc   = (int*)carve((size_t)3 * E * 4);
    unsigned* ebin   = (unsigned*)carve((size_t)3 * E * 4);
    float4*   elr    = (float4*)carve((size_t)3 * N * 16);
    float*    bnsum  = (float*)carve(256 * 4);
    float*    bsum   = (float*)carve((size_t)2 * 128 * 4);
    short*    Wtg    = (short*)carve((size_t)6 * 16384 * 2);
    short*    Wcb    = (short*)carve((size_t)8192 * 2);
    short*    hA     = (short*)carve((size_t)N * 128 * 2);
    short*    hB     = (short*)carve((size_t)N * 128 * 2);
    short*    featb  = (short*)carve((size_t)3 * N * 128 * 2);

    // weight prep + input conversion
    k_wprep<<<(6 * 16384 + 255) / 256, 256, 0, stream>>>(Ws, Wtg);
    k_wprep2<<<(8192 + 256 + 255) / 256, 256, 0, stream>>>(clf_W, bs, Wcb, bsum);
    k_cvt<<<2048, 256, 0, stream>>>(feat_in, hA, N * 128);

    // CSR build via binned sort
    hipMemsetAsync(bcnt, 0, (size_t)3 * NB * 4, stream);
    dim3 gchunk((E + 4095) / 4096, 3);
    k_bhist<<<gchunk, 256, 0, stream>>>(dst, bcnt);
    k_bscan<<<3, 64, 0, stream>>>(bcnt, bptr, bcur);
    k_bin<<<gchunk, 256, 0, stream>>>(src, dst, bcur, ebin);
    dim3 gbkt(NB, 3);
    k_nhist<<<gbkt, 256, 0, stream>>>(ebin, bptr, rowptr);
    k_scat2<<<gbkt, 256, 0, stream>>>(ebin, bptr, rowptr, csrc);

    int gq = (N + 3) / 4;
    for (int l = 0; l < 2; l++) {
        const short* hin = (l == 0) ? hA : hB;
        short* hout = (l == 0) ? hB : hA;
        k_gemm3<<<(N + 127) / 128, 256, 0, stream>>>(hin, Wtg + (size_t)l * 3 * 16384,
                                                     als + (size_t)l * 384, ars + (size_t)l * 384,
                                                     featb, elr, N);
        k_agg3<<<gq, 256, 0, stream>>>(featb, elr, rowptr, csrc,
                                       bsum + (size_t)l * 128, hout, N);
    }

    // BN + classifier on hA (layer-2 output, relu'd bf16)
    hipMemsetAsync(bnsum, 0, 256 * 4, stream);
    k_bnstat<<<512, 256, 0, stream>>>(hA, bnsum, N);
    k_clf<<<(N + 127) / 128, 256, 0, stream>>>(hA, bnsum, bn_w, bn_b, Wcb, clf_b, out, N);
}

// Round 15
// 353.669 us; speedup vs baseline: 1.1160x; 1.0011x over previous
//
#include <hip/hip_runtime.h>
#include <hip/hip_bf16.h>

#define N_NODES 100000
#define N_EDGES 500000
#define HID 128
#define NEG_SLOPE 0.2f
#define NB 98           // buckets of 1024 nodes: ceil(100000/1024)

typedef __attribute__((ext_vector_type(8))) short short8v;
typedef __attribute__((ext_vector_type(4))) short short4v;
typedef __attribute__((ext_vector_type(4))) float f32x4;
typedef __attribute__((ext_vector_type(4))) unsigned uint4v;

__device__ __forceinline__ short f2bf(float x) {
    union { float f; unsigned u; } v; v.f = x;
    unsigned r = v.u + 0x7fff + ((v.u >> 16) & 1);  // RNE
    return (short)(r >> 16);
}
__device__ __forceinline__ unsigned cvtpk(float lo_, float hi_) {  // RNE pack: [bf16(lo) | bf16(hi)<<16]
    unsigned r;
    asm("v_cvt_pk_bf16_f32 %0, %1, %2" : "=v"(r) : "v"(lo_), "v"(hi_));
    return r;
}
__device__ __forceinline__ float frcp(float x) { return __builtin_amdgcn_rcpf(x); }
__device__ __forceinline__ float bflo(unsigned u) {
    union { unsigned x; float f; } c; c.x = u << 16; return c.f;
}
__device__ __forceinline__ float bfhi(unsigned u) {
    union { unsigned x; float f; } c; c.x = u & 0xffff0000u; return c.f;
}
__device__ __forceinline__ float bfs(short s) {
    union { unsigned x; float f; } c; c.x = ((unsigned)(unsigned short)s) << 16; return c.f;
}
__device__ __forceinline__ float asf(unsigned u) {
    union { unsigned x; float f; } c; c.x = u; return c.f;
}
__device__ __forceinline__ float rlf(float x, int i) {
    return asf((unsigned)__builtin_amdgcn_readlane((int)__float_as_uint(x), i));
}

// ---------------- CSR build: binned two-level sort ----------------

__global__ __launch_bounds__(256) void k_bhist(const int* __restrict__ dst, int* __restrict__ bcnt) {
    int r = blockIdx.y, tid = threadIdx.x;
    int base = blockIdx.x * 4096;
    __shared__ int h[128];
    if (tid < 128) h[tid] = 0;
    __syncthreads();
    size_t eb = (size_t)r * N_EDGES;
    int lim = min(base + 4096, N_EDGES);
    for (int e = base + tid; e < lim; e += 256) atomicAdd(&h[dst[eb + e] >> 10], 1);
    __syncthreads();
    if (tid < NB && h[tid]) atomicAdd(&bcnt[r * NB + tid], h[tid]);
}

__global__ void k_bscan(const int* __restrict__ bcnt, int* __restrict__ bptr, int* __restrict__ bcur) {
    int r = blockIdx.x, lane = threadIdx.x;
    int carry = 0;
    for (int base = 0; base < NB; base += 64) {
        int i = base + lane;
        int c = (i < NB) ? bcnt[r * NB + i] : 0;
        int v = c;
        #pragma unroll
        for (int d = 1; d < 64; d <<= 1) { int t = __shfl_up(v, d); if (lane >= d) v += t; }
        int excl = carry + v - c;
        if (i < NB) { bptr[r * (NB + 1) + i] = excl; bcur[r * NB + i] = excl; }
        carry += __shfl(v, 63);
    }
    if (lane == 0) bptr[r * (NB + 1) + NB] = carry;
}

// bin edges into bucket regions of ebin packed as ((dst&1023)<<17 | src)
__global__ __launch_bounds__(256) void k_bin(const int* __restrict__ src, const int* __restrict__ dst,
                                             int* __restrict__ bcur, unsigned* __restrict__ ebin) {
    int r = blockIdx.y, tid = threadIdx.x;
    int base = blockIdx.x * 4096;
    __shared__ int cnt[128], incl[128], gb[128], wcur[128];
    __shared__ uint2 stage[4096];
    if (tid < 128) cnt[tid] = 0;
    __syncthreads();
    int myd[16], mys[16];
    size_t eb = (size_t)r * N_EDGES;
    #pragma unroll
    for (int i = 0; i < 16; i++) {
        int e = base + i * 256 + tid;
        if (e < N_EDGES) {
            int d = dst[eb + e];
            myd[i] = d; mys[i] = src[eb + e];
            atomicAdd(&cnt[d >> 10], 1);
        } else myd[i] = -1;
    }
    __syncthreads();
    if (tid < 128) incl[tid] = cnt[tid];
    __syncthreads();
    for (int d = 1; d < 128; d <<= 1) {
        int t = 0;
        if (tid < 128 && tid >= d) t = incl[tid - d];
        __syncthreads();
        if (tid < 128 && tid >= d) incl[tid] += t;
        __syncthreads();
    }
    if (tid < 128) {
        wcur[tid] = incl[tid] - cnt[tid];
        gb[tid] = (tid < NB && cnt[tid] > 0) ? atomicAdd(&bcur[r * NB + tid], cnt[tid]) : 0;
    }
    __syncthreads();
    #pragma unroll
    for (int i = 0; i < 16; i++) {
        if (myd[i] >= 0) {
            int bkt = myd[i] >> 10;
            int p = atomicAdd(&wcur[bkt], 1);
            stage[p] = make_uint2((unsigned)myd[i], (unsigned)mys[i]);
        }
    }
    __syncthreads();
    int tot = min(4096, N_EDGES - base);
    for (int i = tid; i < tot; i += 256) {
        uint2 u = stage[i];
        int bkt = (int)(u.x >> 10);
        int ex = incl[bkt] - cnt[bkt];
        ebin[eb + gb[bkt] + (i - ex)] = ((u.x & 1023u) << 17) | u.y;
    }
}

__global__ __launch_bounds__(256) void k_nhist(const unsigned* __restrict__ ebin,
                                               const int* __restrict__ bptr,
                                               int* __restrict__ rowptr) {
    int b = blockIdx.x, r = blockIdx.y, tid = threadIdx.x;
    __shared__ int cnt[1024];
    __shared__ int wsum[4];
    for (int i = tid; i < 1024; i += 256) cnt[i] = 0;
    __syncthreads();
    int es = bptr[r * (NB + 1) + b], ee = bptr[r * (NB + 1) + b + 1];
    size_t eb = (size_t)r * N_EDGES;
    for (int i = es + tid; i < ee; i += 256) atomicAdd(&cnt[(ebin[eb + i] >> 17) & 1023u], 1);
    __syncthreads();
    int b4 = tid * 4;
    int c0 = cnt[b4], c1 = cnt[b4 + 1], c2 = cnt[b4 + 2], c3 = cnt[b4 + 3];
    int ts = c0 + c1 + c2 + c3;
    int lane = tid & 63, wid = tid >> 6;
    int v = ts;
    #pragma unroll
    for (int d = 1; d < 64; d <<= 1) { int t = __shfl_up(v, d); if (lane >= d) v += t; }
    if (lane == 63) wsum[wid] = v;
    __syncthreads();
    int woff = 0;
    for (int w = 0; w < wid; w++) woff += wsum[w];
    int p = woff + v - ts;
    int node0 = b << 10;
    int rp = r * (N_NODES + 1);
    int nd;
    nd = node0 + b4;     if (nd < N_NODES) rowptr[rp + nd] = es + p; p += c0;
    nd = node0 + b4 + 1; if (nd < N_NODES) rowptr[rp + nd] = es + p; p += c1;
    nd = node0 + b4 + 2; if (nd < N_NODES) rowptr[rp + nd] = es + p; p += c2;
    nd = node0 + b4 + 3; if (nd < N_NODES) rowptr[rp + nd] = es + p;
    if (b == NB - 1 && tid == 0) rowptr[rp + N_NODES] = bptr[r * (NB + 1) + NB];
}

__global__ __launch_bounds__(256) void k_scat2(const unsigned* __restrict__ ebin,
                                               const int* __restrict__ bptr,
                                               const int* __restrict__ rowptr,
                                               int* __restrict__ csrc) {
    int b = blockIdx.x, r = blockIdx.y, tid = threadIdx.x;
    __shared__ int cnt[1024];
    __shared__ int rloc[1024];
    __shared__ int stage[8192];
    int node0 = b << 10;
    int rp = r * (N_NODES + 1);
    int rs = rowptr[rp + node0];
    for (int i = tid; i < 1024; i += 256) {
        cnt[i] = 0;
        int nd = node0 + i; if (nd > N_NODES) nd = N_NODES;
        rloc[i] = rowptr[rp + nd] - rs;
    }
    __syncthreads();
    int es = bptr[r * (NB + 1) + b], ee = bptr[r * (NB + 1) + b + 1];
    int sz = ee - es;
    size_t eb = (size_t)r * N_EDGES;
    if (sz <= 8192) {
        for (int i = es + tid; i < ee; i += 256) {
            unsigned u = ebin[eb + i];
            int dl = (int)((u >> 17) & 1023u);
            int rk = atomicAdd(&cnt[dl], 1);
            stage[rloc[dl] + rk] = (int)(u & 0x1FFFFu);
        }
        __syncthreads();
        for (int i = tid; i < sz; i += 256) csrc[eb + rs + i] = stage[i];
    } else {
        for (int i = es + tid; i < ee; i += 256) {
            unsigned u = ebin[eb + i];
            int dl = (int)((u >> 17) & 1023u);
            int rk = atomicAdd(&cnt[dl], 1);
            csrc[eb + rs + rloc[dl] + rk] = (int)(u & 0x1FFFFu);
        }
    }
}

// ---------------- W prep: f32 [k][col] -> bf16 [col][k ^ ((col&7)<<3)] ----------------
__global__ void k_wprep(const float* __restrict__ Ws, short* __restrict__ Wt) {
    int i = blockIdx.x * blockDim.x + threadIdx.x;
    if (i < 6 * 16384) {
        int lr = i >> 14, rem = i & 16383, k = rem >> 7, col = rem & 127;
        Wt[lr * 16384 + col * 128 + (k ^ ((col & 7) << 3))] = f2bf(Ws[i]);
    }
}

// clf_W f32 [128 k][64 col] -> bf16 [col][k ^ ((col&7)<<3)]; also bias sums per layer
__global__ void k_wprep2(const float* __restrict__ Wc, const float* __restrict__ bs,
                         short* __restrict__ Wcb, float* __restrict__ bsum) {
    int i = blockIdx.x * blockDim.x + threadIdx.x;
    if (i < 8192) {
        int k = i >> 6, col = i & 63;
        Wcb[col * 128 + (k ^ ((col & 7) << 3))] = f2bf(Wc[i]);
    } else if (i < 8192 + 256) {
        int j = i - 8192;
        int l = j >> 7, c = j & 127;
        bsum[j] = bs[(l * 3 + 0) * 128 + c] + bs[(l * 3 + 1) * 128 + c] + bs[(l * 3 + 2) * 128 + c];
    }
}

// ---------------- f32 -> bf16 bulk convert ----------------
__global__ void k_cvt(const float* __restrict__ in, short* __restrict__ out, int n) {
    int i = blockIdx.x * blockDim.x + threadIdx.x;
    int stride = gridDim.x * blockDim.x;
    for (int base = i * 8; base < n; base += stride * 8) {
        float4 x = *(const float4*)(in + base);
        float4 y = *(const float4*)(in + base + 4);
        uint4v o;
        o[0] = cvtpk(x.x, x.y); o[1] = cvtpk(x.z, x.w);
        o[2] = cvtpk(y.x, y.y); o[3] = cvtpk(y.z, y.w);
        *(uint4v*)(out + base) = o;
    }
}

// ---------------- MFMA GEMM over 3 relations in one dispatch: featb[r] bf16 + fused el/er ----------------
__global__ __launch_bounds__(256) void k_gemm3(const short* __restrict__ Abf,
                                               const short* __restrict__ Wt3,    // 3 x 16384, pre-swizzled
                                               const float* __restrict__ al3,    // [3][128]
                                               const float* __restrict__ ar3,    // [3][128]
                                               short* __restrict__ featb,        // [3][N*128]
                                               float4* __restrict__ elr,         // [3][N]
                                               int nrows) {
    __shared__ __align__(16) short Wl[128 * 128];
    int tid = threadIdx.x;
    int lane = tid & 63, wid = tid >> 6;
    int q = lane >> 4, j = lane & 15;
    int rowbase = blockIdx.x * 128 + wid * 32;

    // A fragments once (shared by all 3 relations)
    short8v a[2][4];
    #pragma unroll
    for (int rb = 0; rb < 2; rb++) {
        int row = rowbase + rb * 16 + j;
        const short* ap = Abf + (size_t)row * 128 + q * 8;
        bool ok = row < nrows;
        #pragma unroll
        for (int kk = 0; kk < 4; kk++)
            a[rb][kk] = ok ? *(const short8v*)(ap + kk * 32) : (short8v)0;
    }

    for (int cr = 0; cr < 3; cr++) {
        if (cr) __syncthreads();   // all waves done reading Wl before overwrite
        {
            const float4* srcv = (const float4*)(Wt3 + cr * 16384);
            float4* dstv = (float4*)Wl;
            #pragma unroll
            for (int i = 0; i < 8; i++) dstv[tid + i * 256] = srcv[tid + i * 256];
        }
        float alv[8], arv[8];
        #pragma unroll
        for (int cb = 0; cb < 8; cb++) {
            alv[cb] = al3[cr * 128 + cb * 16 + j];
            arv[cb] = ar3[cr * 128 + cb * 16 + j];
        }
        __syncthreads();

        f32x4 acc[2][8] = {};
        #pragma unroll
        for (int cb = 0; cb < 8; cb++) {
            int col = cb * 16 + j;
            const short* wp = Wl + col * 128;
            int sw = (col & 7) << 3;
            #pragma unroll
            for (int kk = 0; kk < 4; kk++) {
                short8v b = *(const short8v*)(wp + ((kk * 32 + q * 8) ^ sw));
                acc[0][cb] = __builtin_amdgcn_mfma_f32_16x16x32_bf16(a[0][kk], b, acc[0][cb], 0, 0, 0);
                acc[1][cb] = __builtin_amdgcn_mfma_f32_16x16x32_bf16(a[1][kk], b, acc[1][cb], 0, 0, 0);
            }
        }

        short* outB = featb + (size_t)cr * N_NODES * 128;
        #pragma unroll
        for (int rb = 0; rb < 2; rb++) {
            int row0 = rowbase + rb * 16 + q * 4;
            #pragma unroll
            for (int reg = 0; reg < 4; reg++) {
                int row = row0 + reg;
                if (row < nrows) {
                    short* op = outB + (size_t)row * 128 + j;
                    #pragma unroll
                    for (int cb = 0; cb < 8; cb++) op[cb * 16] = f2bf(acc[rb][cb][reg]);
                }
            }
        }

        // fused el/er
        float4* elro = elr + (size_t)cr * N_NODES;
        #pragma unroll
        for (int rb = 0; rb < 2; rb++) {
            float e0[4], e1[4], r0[4], r1[4];
            #pragma unroll
            for (int reg = 0; reg < 4; reg++) {
                float se0 = 0.f, se1 = 0.f, sr0 = 0.f, sr1 = 0.f;
                #pragma unroll
                for (int cb = 0; cb < 4; cb++) {
                    se0 += acc[rb][cb][reg] * alv[cb];
                    sr0 += acc[rb][cb][reg] * arv[cb];
                    se1 += acc[rb][cb + 4][reg] * alv[cb + 4];
                    sr1 += acc[rb][cb + 4][reg] * arv[cb + 4];
                }
                #pragma unroll
                for (int off = 1; off < 16; off <<= 1) {
                    se0 += __shfl_xor(se0, off);
                    se1 += __shfl_xor(se1, off);
                    sr0 += __shfl_xor(sr0, off);
                    sr1 += __shfl_xor(sr1, off);
                }
                e0[reg] = se0; e1[reg] = se1; r0[reg] = sr0; r1[reg] = sr1;
            }
            if (j < 4) {
                int row = rowbase + rb * 16 + q * 4 + j;
                if (row < nrows) {
                    float4 v;
                    v.x = j == 0 ? e0[0] : j == 1 ? e0[1] : j == 2 ? e0[2] : e0[3];
                    v.y = j == 0 ? e1[0] : j == 1 ? e1[1] : j == 2 ? e1[2] : e1[3];
                    v.z = j == 0 ? r0[0] : j == 1 ? r0[1] : j == 2 ? r0[2] : r0[3];
                    v.w = j == 0 ? r1[0] : j == 1 ? r1[1] : j == 2 ? r1[2] : r1[3];
                    elro[row] = v;
                }
            }
        }
    }
}

// ---------------- merged 3-relation softmax + gather-aggregate (wave per dst node) ----------------
// Concatenated lane space + scan-based per-relation softmax + prescaled packed alpha.
// v_rcp for normalization, v_cvt_pk_bf16_f32 for packing.
__global__ __launch_bounds__(256) void k_agg3(const short* __restrict__ feat,   // [3][N*128]
                                              const float4* __restrict__ elr,   // [3][N]
                                              const int* __restrict__ rowptr,   // [3][N+1]
                                              const int* __restrict__ csrc,     // [3][E]
                                              const float* __restrict__ bsum,   // [128] summed bias
                                              short* __restrict__ outB, int nrows) {
    int wid = threadIdx.x >> 6, lane = threadIdx.x & 63;
    int v = (blockIdx.x << 2) + wid;
    if (v >= nrows) return;
    int c0 = lane << 1;
    bool lo = lane < 32;
    unsigned psel = lo ? 0x01000404u : 0x03020404u;   // dest=[0,0,bk,bk+1] from s1 bytes

    int beg[3], deg[3];
    #pragma unroll
    for (int r = 0; r < 3; r++) {
        beg[r] = rowptr[r * (N_NODES + 1) + v];
        deg[r] = rowptr[r * (N_NODES + 1) + v + 1] - beg[r];
    }
    float4 ev0 = elr[v];
    float4 ev1 = elr[(size_t)N_NODES + v];
    float4 ev2 = elr[(size_t)2 * N_NODES + v];
    int tc = deg[0] + deg[1] + deg[2];

    float2 bv = *(const float2*)(bsum + c0);
    float t0 = bv.x, t1 = bv.y;

    if (tc <= 64) {
        int b0 = deg[0], b01 = deg[0] + deg[1];
        int rsel = (lane >= b0 ? 1 : 0) + (lane >= b01 ? 1 : 0);
        int rofs = rsel == 0 ? 0 : (rsel == 1 ? b0 : b01);
        int idx = lane - rofs;
        bool val = lane < tc;
        float evz = rsel == 0 ? ev0.z : (rsel == 1 ? ev1.z : ev2.z);
        float evw = rsel == 0 ? ev0.w : (rsel == 1 ? ev1.w : ev2.w);
        int s = val ? csrc[(size_t)rsel * N_EDGES + beg[rsel] + idx] : 0;
        float4 es = elr[(size_t)rsel * N_NODES + s];
        float e0 = es.x + evz; e0 = e0 >= 0.f ? e0 : NEG_SLOPE * e0;
        float e1 = es.y + evw; e1 = e1 >= 0.f ? e1 : NEG_SLOPE * e1;
        float p0 = val ? __expf(e0) : 0.f;
        float p1 = val ? __expf(e1) : 0.f;

        // inclusive wave scan of (p0, p1)
        float s0 = p0, s1 = p1;
        #pragma unroll
        for (int d = 1; d < 64; d <<= 1) {
            float u0 = __shfl_up(s0, d), u1 = __shfl_up(s1, d);
            if (lane >= d) { s0 += u0; s1 += u1; }
        }
        // per-relation sums from scan boundaries (uniform indices)
        float E00 = (b0 > 0) ? rlf(s0, b0 - 1) : 0.f;
        float E01 = (b01 > b0) ? rlf(s0, b01 - 1) : E00;
        float E02 = (tc > b01) ? rlf(s0, tc - 1) : E01;
        float E10 = (b0 > 0) ? rlf(s1, b0 - 1) : 0.f;
        float E11 = (b01 > b0) ? rlf(s1, b01 - 1) : E10;
        float E12 = (tc > b01) ? rlf(s1, tc - 1) : E11;
        float m00 = E00, m01 = E01 - E00, m02 = E02 - E01;
        float m10 = E10, m11 = E11 - E10, m12 = E12 - E11;
        float i00 = m00 > 0.f ? frcp(m00) : 0.f;
        float i01 = m01 > 0.f ? frcp(m01) : 0.f;
        float i02 = m02 > 0.f ? frcp(m02) : 0.f;
        float i10 = m10 > 0.f ? frcp(m10) : 0.f;
        float i11 = m11 > 0.f ? frcp(m11) : 0.f;
        float i12 = m12 > 0.f ? frcp(m12) : 0.f;
        float iv0 = rsel == 0 ? i00 : (rsel == 1 ? i01 : i02);
        float iv1 = rsel == 0 ? i10 : (rsel == 1 ? i11 : i12);
        unsigned pkl = cvtpk(p0 * iv0, p1 * iv1);   // invalid lanes: p=0 -> 0 pack
        int addr = (rsel * N_NODES + s) << 7;   // element offset of feat row

        float xa = 0.f, xb = 0.f, ya = 0.f, yb = 0.f;
        for (int j0 = 0; j0 < tc; j0 += 4) {
            int a0_ = __builtin_amdgcn_readlane(addr, j0);
            int a1_ = __builtin_amdgcn_readlane(addr, j0 + 1);
            int a2_ = __builtin_amdgcn_readlane(addr, j0 + 2);
            int a3_ = __builtin_amdgcn_readlane(addr, j0 + 3);
            unsigned b0_ = (unsigned)__builtin_amdgcn_readlane((int)pkl, j0);
            unsigned b1_ = (unsigned)__builtin_amdgcn_readlane((int)pkl, j0 + 1);
            unsigned b2_ = (unsigned)__builtin_amdgcn_readlane((int)pkl, j0 + 2);
            unsigned b3_ = (unsigned)__builtin_amdgcn_readlane((int)pkl, j0 + 3);
            unsigned u0 = *(const unsigned*)(feat + (size_t)(unsigned)a0_ + c0);
            unsigned u1 = *(const unsigned*)(feat + (size_t)(unsigned)a1_ + c0);
            unsigned u2 = *(const unsigned*)(feat + (size_t)(unsigned)a2_ + c0);
            unsigned u3 = *(const unsigned*)(feat + (size_t)(unsigned)a3_ + c0);
            float q0 = asf(__builtin_amdgcn_perm(0u, b0_, psel));
            float q1 = asf(__builtin_amdgcn_perm(0u, b1_, psel));
            float q2 = asf(__builtin_amdgcn_perm(0u, b2_, psel));
            float q3 = asf(__builtin_amdgcn_perm(0u, b3_, psel));
            xa += q0 * bflo(u0); xb += q0 * bfhi(u0);
            ya += q1 * bflo(u1); yb += q1 * bfhi(u1);
            xa += q2 * bflo(u2); xb += q2 * bfhi(u2);
            ya += q3 * bflo(u3); yb += q3 * bfhi(u3);
        }
        t0 += xa + ya;
        t1 += xb + yb;
    } else {
        // generic fallback: per-relation, 64-chunked, sum + divide at end
        float evzs[3] = {ev0.z, ev1.z, ev2.z};
        float evws[3] = {ev0.w, ev1.w, ev2.w};
        #pragma unroll
        for (int r = 0; r < 3; r++) {
            const short* fb = feat + (size_t)r * (N_NODES * 128);
            float sp = 0.f, a0 = 0.f, a1 = 0.f;
            int e_end = beg[r] + deg[r];
            for (int base = beg[r]; base < e_end; base += 64) {
                int idx = base + lane;
                bool val = idx < e_end;
                int sv2 = val ? csrc[(size_t)r * N_EDGES + idx] : 0;
                float4 es = elr[(size_t)r * N_NODES + sv2];
                float e0 = es.x + evzs[r]; e0 = e0 >= 0.f ? e0 : NEG_SLOPE * e0;
                float e1 = es.y + evws[r]; e1 = e1 >= 0.f ? e1 : NEG_SLOPE * e1;
                float q0v = val ? __expf(e0) : 0.f;
                float q1v = val ? __expf(e1) : 0.f;
                int bcn = min(64, e_end - base);
                for (int k = 0; k < bcn; k++) {
                    int ss = __builtin_amdgcn_readlane(sv2, k);
                    float q0 = rlf(q0v, k), q1 = rlf(q1v, k);
                    float pp = lo ? q0 : q1;
                    unsigned u = *(const unsigned*)(fb + ((size_t)(unsigned)ss << 7) + c0);
                    sp += pp;
                    a0 += pp * bflo(u);
                    a1 += pp * bfhi(u);
                }
            }
            float inv = sp > 0.f ? frcp(sp) : 0.f;
            t0 += a0 * inv;
            t1 += a1 * inv;
        }
    }

    unsigned pko = cvtpk(fmaxf(t0, 0.f), fmaxf(t1, 0.f));
    *(unsigned*)(outB + (size_t)v * 128 + c0) = pko;
}

// ---------------- BN stats (bf16 relu'd input, vectorized) ----------------
__global__ __launch_bounds__(256) void k_bnstat(const short* __restrict__ h,
                                                float* __restrict__ sums, int nrows) {
    int tid = threadIdx.x;
    int cg = tid & 15, rgrp = tid >> 4;
    float s[8] = {}, q[8] = {};
    for (int row = blockIdx.x * 16 + rgrp; row < nrows; row += gridDim.x * 16) {
        short8v u = *(const short8v*)(h + (size_t)row * 128 + cg * 8);
        #pragma unroll
        for (int i = 0; i < 8; i++) {
            float x = bfs(u[i]);
            s[i] += x; q[i] += x * x;
        }
    }
    __shared__ float ls[16][128];
    __shared__ float lq[16][128];
    #pragma unroll
    for (int i = 0; i < 8; i++) { ls[rgrp][cg * 8 + i] = s[i]; lq[rgrp][cg * 8 + i] = q[i]; }
    __syncthreads();
    int t = tid;
    if (t < 128) {
        float ts = 0.f, tq = 0.f;
        #pragma unroll
        for (int g = 0; g < 16; g++) { ts += ls[g][t]; tq += lq[g][t]; }
        atomicAdd(&sums[t], ts);
        atomicAdd(&sums[128 + t], tq);
    }
}

// ---------------- classifier: BN-normalize (input pre-relu'd bf16) -> MFMA GEMM [N,128]x[128,64] ----------------
__global__ __launch_bounds__(256) void k_clf(const short* __restrict__ h,
                                             const float* __restrict__ sums,
                                             const float* __restrict__ bn_w,
                                             const float* __restrict__ bn_b,
                                             const short* __restrict__ Wcb,
                                             const float* __restrict__ cbias,
                                             float* __restrict__ out, int nrows) {
    __shared__ __align__(16) short Wl[64 * 128];
    __shared__ float2 bnp[128];
    int tid = threadIdx.x;
    {
        const float4* srcv = (const float4*)Wcb;
        float4* dstv = (float4*)Wl;
        #pragma unroll
        for (int i = 0; i < 4; i++) dstv[tid + i * 256] = srcv[tid + i * 256];
    }
    if (tid < 128) {
        float mu = sums[tid] / (float)nrows;
        float var = sums[128 + tid] / (float)nrows - mu * mu;
        float rs = rsqrtf(var + 1e-5f);
        float sc = bn_w[tid] * rs;
        bnp[tid] = make_float2(sc, bn_b[tid] - mu * sc);
    }
    __syncthreads();

    int lane = tid & 63, wid = tid >> 6;
    int q = lane >> 4, j = lane & 15;
    int rowbase = blockIdx.x * 128 + wid * 32;

    float cbv[4];
    #pragma unroll
    for (int cb = 0; cb < 4; cb++) cbv[cb] = cbias[cb * 16 + j];

    short8v a[2][4];
    #pragma unroll
    for (int rb = 0; rb < 2; rb++) {
        int row = rowbase + rb * 16 + j;
        bool ok = row < nrows;
        const short* hp = h + (size_t)row * 128 + q * 8;
        #pragma unroll
        for (int kk = 0; kk < 4; kk++) {
            short8v u = ok ? *(const short8v*)(hp + kk * 32) : (short8v)0;
            int k0 = kk * 32 + q * 8;
            short8v av;
            #pragma unroll
            for (int i = 0; i < 8; i++) {
                float2 bp = bnp[k0 + i];
                av[i] = f2bf(bfs(u[i]) * bp.x + bp.y);
            }
            a[rb][kk] = av;
        }
    }

    f32x4 acc[2][4] = {};
    #pragma unroll
    for (int cb = 0; cb < 4; cb++) {
        int col = cb * 16 + j;
        const short* wp = Wl + col * 128;
        int sw = (col & 7) << 3;
        #pragma unroll
        for (int kk = 0; kk < 4; kk++) {
            short8v b = *(const short8v*)(wp + ((kk * 32 + q * 8) ^ sw));
            acc[0][cb] = __builtin_amdgcn_mfma_f32_16x16x32_bf16(a[0][kk], b, acc[0][cb], 0, 0, 0);
            acc[1][cb] = __builtin_amdgcn_mfma_f32_16x16x32_bf16(a[1][kk], b, acc[1][cb], 0, 0, 0);
        }
    }

    #pragma unroll
    for (int rb = 0; rb < 2; rb++) {
        int row0 = rowbase + rb * 16 + q * 4;
        #pragma unroll
        for (int reg = 0; reg < 4; reg++) {
            int row = row0 + reg;
            if (row < nrows) {
                float* op = out + (size_t)row * 64 + j;
                #pragma unroll
                for (int cb = 0; cb < 4; cb++) op[cb * 16] = acc[rb][cb][reg] + cbv[cb];
            }
        }
    }
}

// ---------------- launch ----------------

extern "C" void kernel_launch(void* const* d_in, const int* in_sizes, int n_in,
                              void* d_out, int out_size, void* d_ws, size_t ws_size,
                              hipStream_t stream) {
    (void)in_sizes; (void)n_in; (void)out_size; (void)ws_size;
    const float* feat_in = (const float*)d_in[0];
    const float* Ws      = (const float*)d_in[1];
    const float* als     = (const float*)d_in[2];
    const float* ars     = (const float*)d_in[3];
    const float* bs      = (const float*)d_in[4];
    const float* bn_w    = (const float*)d_in[5];
    const float* bn_b    = (const float*)d_in[6];
    const float* clf_W   = (const float*)d_in[7];
    const float* clf_b   = (const float*)d_in[8];
    const int*   src     = (const int*)d_in[9];
    const int*   dst     = (const int*)d_in[10];
    float* out = (float*)d_out;

    const int N = N_NODES, E = N_EDGES;
    char* p = (char*)d_ws;
    auto carve = [&](size_t bytes) { char* q = p; p += (bytes + 255) & ~255ULL; return q; };
    int*      bcnt   = (int*)carve((size_t)3 * NB * 4);
    int*      bptr   = (int*)carve((size_t)3 * (NB + 1) * 4);
    int*      bcur   = (int*)carve((size_t)3 * NB * 4);
    int*      rowptr = (int*)carve((size_t)3 * (N + 1) * 4);
    int*      csrc   = (int*)carve((size_t)3 * E * 4);
    unsigned* ebin   = (unsigned*)carve((size_t)3 * E * 4);
    float4*   elr    = (float4*)carve((size_t)3 * N * 16);
    float*    bnsum  = (float*)carve(256 * 4);
    float*    bsum   = (float*)carve((size_t)2 * 128 * 4);
    short*    Wtg    = (short*)carve((size_t)6 * 16384 * 2);
    short*    Wcb    = (short*)carve((size_t)8192 * 2);
    short*    hA     = (short*)carve((size_t)N * 128 * 2);
    short*    hB     = (short*)carve((size_t)N * 128 * 2);
    short*    featb  = (short*)carve((size_t)3 * N * 128 * 2);

    // weight prep + input conversion
    k_wprep<<<(6 * 16384 + 255) / 256, 256, 0, stream>>>(Ws, Wtg);
    k_wprep2<<<(8192 + 256 + 255) / 256, 256, 0, stream>>>(clf_W, bs, Wcb, bsum);
    k_cvt<<<2048, 256, 0, stream>>>(feat_in, hA, N * 128);

    // CSR build via binned sort
    hipMemsetAsync(bcnt, 0, (size_t)3 * NB * 4, stream);
    dim3 gchunk((E + 4095) / 4096, 3);
    k_bhist<<<gchunk, 256, 0, stream>>>(dst, bcnt);
    k_bscan<<<3, 64, 0, stream>>>(bcnt, bptr, bcur);
    k_bin<<<gchunk, 256, 0, stream>>>(src, dst, bcur, ebin);
    dim3 gbkt(NB, 3);
    k_nhist<<<gbkt, 256, 0, stream>>>(ebin, bptr, rowptr);
    k_scat2<<<gbkt, 256, 0, stream>>>(ebin, bptr, rowptr, csrc);

    int gq = (N + 3) / 4;
    for (int l = 0; l < 2; l++) {
        const short* hin = (l == 0) ? hA : hB;
        short* hout = (l == 0) ? hB : hA;
        k_gemm3<<<(N + 127) / 128, 256, 0, stream>>>(hin, Wtg + (size_t)l * 3 * 16384,
                                                     als + (size_t)l * 384, ars + (size_t)l * 384,
                                                     featb, elr, N);
        k_agg3<<<gq, 256, 0, stream>>>(featb, elr, rowptr, csrc,
                                       bsum + (size_t)l * 128, hout, N);
    }

    // BN + classifier on hA (layer-2 output, relu'd bf16)
    hipMemsetAsync(bnsum, 0, 256 * 4, stream);
    k_bnstat<<<512, 256, 0, stream>>>(hA, bnsum, N);
    k_clf<<<(N + 127) / 128, 256, 0, stream>>>(hA, bnsum, bn_w, bn_b, Wcb, clf_b, out, N);
}

// Round 16
// 349.447 us; speedup vs baseline: 1.1295x; 1.0121x over previous
//
#include <hip/hip_runtime.h>
#include <hip/hip_bf16.h>

#define N_NODES 100000
#define N_EDGES 500000
#define HID 128
#define NEG_SLOPE 0.2f
#define NB 98           // buckets of 1024 nodes: ceil(100000/1024)

typedef __attribute__((ext_vector_type(8))) short short8v;
typedef __attribute__((ext_vector_type(4))) short short4v;
typedef __attribute__((ext_vector_type(4))) float f32x4;
typedef __attribute__((ext_vector_type(4))) unsigned uint4v;

__device__ __forceinline__ short f2bf(float x) {
    union { float f; unsigned u; } v; v.f = x;
    unsigned r = v.u + 0x7fff + ((v.u >> 16) & 1);  // RNE
    return (short)(r >> 16);
}
__device__ __forceinline__ unsigned cvtpk(float lo_, float hi_) {  // RNE pack: [bf16(lo) | bf16(hi)<<16]
    unsigned r;
    asm("v_cvt_pk_bf16_f32 %0, %1, %2" : "=v"(r) : "v"(lo_), "v"(hi_));
    return r;
}
__device__ __forceinline__ float frcp(float x) { return __builtin_amdgcn_rcpf(x); }
__device__ __forceinline__ float bflo(unsigned u) {
    union { unsigned x; float f; } c; c.x = u << 16; return c.f;
}
__device__ __forceinline__ float bfhi(unsigned u) {
    union { unsigned x; float f; } c; c.x = u & 0xffff0000u; return c.f;
}
__device__ __forceinline__ float bfs(short s) {
    union { unsigned x; float f; } c; c.x = ((unsigned)(unsigned short)s) << 16; return c.f;
}
__device__ __forceinline__ float asf(unsigned u) {
    union { unsigned x; float f; } c; c.x = u; return c.f;
}
__device__ __forceinline__ float rlf(float x, int i) {
    return asf((unsigned)__builtin_amdgcn_readlane((int)__float_as_uint(x), i));
}

// ---------------- CSR build: binned two-level sort ----------------

__global__ __launch_bounds__(256) void k_bhist(const int* __restrict__ dst, int* __restrict__ bcnt) {
    int r = blockIdx.y, tid = threadIdx.x;
    int base = blockIdx.x * 4096;
    __shared__ int h[128];
    if (tid < 128) h[tid] = 0;
    __syncthreads();
    size_t eb = (size_t)r * N_EDGES;
    int lim = min(base + 4096, N_EDGES);
    for (int e = base + tid; e < lim; e += 256) atomicAdd(&h[dst[eb + e] >> 10], 1);
    __syncthreads();
    if (tid < NB && h[tid]) atomicAdd(&bcnt[r * NB + tid], h[tid]);
}

__global__ void k_bscan(const int* __restrict__ bcnt, int* __restrict__ bptr, int* __restrict__ bcur) {
    int r = blockIdx.x, lane = threadIdx.x;
    int carry = 0;
    for (int base = 0; base < NB; base += 64) {
        int i = base + lane;
        int c = (i < NB) ? bcnt[r * NB + i] : 0;
        int v = c;
        #pragma unroll
        for (int d = 1; d < 64; d <<= 1) { int t = __shfl_up(v, d); if (lane >= d) v += t; }
        int excl = carry + v - c;
        if (i < NB) { bptr[r * (NB + 1) + i] = excl; bcur[r * NB + i] = excl; }
        carry += __shfl(v, 63);
    }
    if (lane == 0) bptr[r * (NB + 1) + NB] = carry;
}

// bin edges into bucket regions of ebin packed as ((dst&1023)<<17 | src)
__global__ __launch_bounds__(256) void k_bin(const int* __restrict__ src, const int* __restrict__ dst,
                                             int* __restrict__ bcur, unsigned* __restrict__ ebin) {
    int r = blockIdx.y, tid = threadIdx.x;
    int base = blockIdx.x * 4096;
    __shared__ int cnt[128], incl[128], gb[128], wcur[128];
    __shared__ uint2 stage[4096];
    if (tid < 128) cnt[tid] = 0;
    __syncthreads();
    int myd[16], mys[16];
    size_t eb = (size_t)r * N_EDGES;
    #pragma unroll
    for (int i = 0; i < 16; i++) {
        int e = base + i * 256 + tid;
        if (e < N_EDGES) {
            int d = dst[eb + e];
            myd[i] = d; mys[i] = src[eb + e];
            atomicAdd(&cnt[d >> 10], 1);
        } else myd[i] = -1;
    }
    __syncthreads();
    if (tid < 128) incl[tid] = cnt[tid];
    __syncthreads();
    for (int d = 1; d < 128; d <<= 1) {
        int t = 0;
        if (tid < 128 && tid >= d) t = incl[tid - d];
        __syncthreads();
        if (tid < 128 && tid >= d) incl[tid] += t;
        __syncthreads();
    }
    if (tid < 128) {
        wcur[tid] = incl[tid] - cnt[tid];
        gb[tid] = (tid < NB && cnt[tid] > 0) ? atomicAdd(&bcur[r * NB + tid], cnt[tid]) : 0;
    }
    __syncthreads();
    #pragma unroll
    for (int i = 0; i < 16; i++) {
        if (myd[i] >= 0) {
            int bkt = myd[i] >> 10;
            int p = atomicAdd(&wcur[bkt], 1);
            stage[p] = make_uint2((unsigned)myd[i], (unsigned)mys[i]);
        }
    }
    __syncthreads();
    int tot = min(4096, N_EDGES - base);
    for (int i = tid; i < tot; i += 256) {
        uint2 u = stage[i];
        int bkt = (int)(u.x >> 10);
        int ex = incl[bkt] - cnt[bkt];
        ebin[eb + gb[bkt] + (i - ex)] = ((u.x & 1023u) << 17) | u.y;
    }
}

__global__ __launch_bounds__(256) void k_nhist(const unsigned* __restrict__ ebin,
                                               const int* __restrict__ bptr,
                                               int* __restrict__ rowptr) {
    int b = blockIdx.x, r = blockIdx.y, tid = threadIdx.x;
    __shared__ int cnt[1024];
    __shared__ int wsum[4];
    for (int i = tid; i < 1024; i += 256) cnt[i] = 0;
    __syncthreads();
    int es = bptr[r * (NB + 1) + b], ee = bptr[r * (NB + 1) + b + 1];
    size_t eb = (size_t)r * N_EDGES;
    for (int i = es + tid; i < ee; i += 256) atomicAdd(&cnt[(ebin[eb + i] >> 17) & 1023u], 1);
    __syncthreads();
    int b4 = tid * 4;
    int c0 = cnt[b4], c1 = cnt[b4 + 1], c2 = cnt[b4 + 2], c3 = cnt[b4 + 3];
    int ts = c0 + c1 + c2 + c3;
    int lane = tid & 63, wid = tid >> 6;
    int v = ts;
    #pragma unroll
    for (int d = 1; d < 64; d <<= 1) { int t = __shfl_up(v, d); if (lane >= d) v += t; }
    if (lane == 63) wsum[wid] = v;
    __syncthreads();
    int woff = 0;
    for (int w = 0; w < wid; w++) woff += wsum[w];
    int p = woff + v - ts;
    int node0 = b << 10;
    int rp = r * (N_NODES + 1);
    int nd;
    nd = node0 + b4;     if (nd < N_NODES) rowptr[rp + nd] = es + p; p += c0;
    nd = node0 + b4 + 1; if (nd < N_NODES) rowptr[rp + nd] = es + p; p += c1;
    nd = node0 + b4 + 2; if (nd < N_NODES) rowptr[rp + nd] = es + p; p += c2;
    nd = node0 + b4 + 3; if (nd < N_NODES) rowptr[rp + nd] = es + p;
    if (b == NB - 1 && tid == 0) rowptr[rp + N_NODES] = bptr[r * (NB + 1) + NB];
}

__global__ __launch_bounds__(256) void k_scat2(const unsigned* __restrict__ ebin,
                                               const int* __restrict__ bptr,
                                               const int* __restrict__ rowptr,
                                               int* __restrict__ csrc) {
    int b = blockIdx.x, r = blockIdx.y, tid = threadIdx.x;
    __shared__ int cnt[1024];
    __shared__ int rloc[1024];
    __shared__ int stage[8192];
    int node0 = b << 10;
    int rp = r * (N_NODES + 1);
    int rs = rowptr[rp + node0];
    for (int i = tid; i < 1024; i += 256) {
        cnt[i] = 0;
        int nd = node0 + i; if (nd > N_NODES) nd = N_NODES;
        rloc[i] = rowptr[rp + nd] - rs;
    }
    __syncthreads();
    int es = bptr[r * (NB + 1) + b], ee = bptr[r * (NB + 1) + b + 1];
    int sz = ee - es;
    size_t eb = (size_t)r * N_EDGES;
    if (sz <= 8192) {
        for (int i = es + tid; i < ee; i += 256) {
            unsigned u = ebin[eb + i];
            int dl = (int)((u >> 17) & 1023u);
            int rk = atomicAdd(&cnt[dl], 1);
            stage[rloc[dl] + rk] = (int)(u & 0x1FFFFu);
        }
        __syncthreads();
        for (int i = tid; i < sz; i += 256) csrc[eb + rs + i] = stage[i];
    } else {
        for (int i = es + tid; i < ee; i += 256) {
            unsigned u = ebin[eb + i];
            int dl = (int)((u >> 17) & 1023u);
            int rk = atomicAdd(&cnt[dl], 1);
            csrc[eb + rs + rloc[dl] + rk] = (int)(u & 0x1FFFFu);
        }
    }
}

// ---------------- W prep: f32 [k][col] -> bf16 [col][k ^ ((col&7)<<3)] ----------------
__global__ void k_wprep(const float* __restrict__ Ws, short* __restrict__ Wt) {
    int i = blockIdx.x * blockDim.x + threadIdx.x;
    if (i < 6 * 16384) {
        int lr = i >> 14, rem = i & 16383, k = rem >> 7, col = rem & 127;
        Wt[lr * 16384 + col * 128 + (k ^ ((col & 7) << 3))] = f2bf(Ws[i]);
    }
}

// clf_W f32 [128 k][64 col] -> bf16 [col][k ^ ((col&7)<<3)]; also bias sums per layer
__global__ void k_wprep2(const float* __restrict__ Wc, const float* __restrict__ bs,
                         short* __restrict__ Wcb, float* __restrict__ bsum) {
    int i = blockIdx.x * blockDim.x + threadIdx.x;
    if (i < 8192) {
        int k = i >> 6, col = i & 63;
        Wcb[col * 128 + (k ^ ((col & 7) << 3))] = f2bf(Wc[i]);
    } else if (i < 8192 + 256) {
        int j = i - 8192;
        int l = j >> 7, c = j & 127;
        bsum[j] = bs[(l * 3 + 0) * 128 + c] + bs[(l * 3 + 1) * 128 + c] + bs[(l * 3 + 2) * 128 + c];
    }
}

// ---------------- f32 -> bf16 bulk convert ----------------
__global__ void k_cvt(const float* __restrict__ in, short* __restrict__ out, int n) {
    int i = blockIdx.x * blockDim.x + threadIdx.x;
    int stride = gridDim.x * blockDim.x;
    for (int base = i * 8; base < n; base += stride * 8) {
        float4 x = *(const float4*)(in + base);
        float4 y = *(const float4*)(in + base + 4);
        uint4v o;
        o[0] = cvtpk(x.x, x.y); o[1] = cvtpk(x.z, x.w);
        o[2] = cvtpk(y.x, y.y); o[3] = cvtpk(y.z, y.w);
        *(uint4v*)(out + base) = o;
    }
}

// ---------------- MFMA GEMM over 3 relations in one dispatch: featb[r] bf16 + fused el/er ----------------
__global__ __launch_bounds__(256) void k_gemm3(const short* __restrict__ Abf,
                                               const short* __restrict__ Wt3,    // 3 x 16384, pre-swizzled
                                               const float* __restrict__ al3,    // [3][128]
                                               const float* __restrict__ ar3,    // [3][128]
                                               short* __restrict__ featb,        // [3][N*128]
                                               float2* __restrict__ el2,         // [3][N] (el_h0, el_h1)
                                               float2* __restrict__ er2,         // [3][N] (er_h0, er_h1)
                                               int nrows) {
    __shared__ __align__(16) short Wl[128 * 128];
    int tid = threadIdx.x;
    int lane = tid & 63, wid = tid >> 6;
    int q = lane >> 4, j = lane & 15;
    int rowbase = blockIdx.x * 128 + wid * 32;

    // A fragments once (shared by all 3 relations)
    short8v a[2][4];
    #pragma unroll
    for (int rb = 0; rb < 2; rb++) {
        int row = rowbase + rb * 16 + j;
        const short* ap = Abf + (size_t)row * 128 + q * 8;
        bool ok = row < nrows;
        #pragma unroll
        for (int kk = 0; kk < 4; kk++)
            a[rb][kk] = ok ? *(const short8v*)(ap + kk * 32) : (short8v)0;
    }

    for (int cr = 0; cr < 3; cr++) {
        if (cr) __syncthreads();   // all waves done reading Wl before overwrite
        {
            const float4* srcv = (const float4*)(Wt3 + cr * 16384);
            float4* dstv = (float4*)Wl;
            #pragma unroll
            for (int i = 0; i < 8; i++) dstv[tid + i * 256] = srcv[tid + i * 256];
        }
        float alv[8], arv[8];
        #pragma unroll
        for (int cb = 0; cb < 8; cb++) {
            alv[cb] = al3[cr * 128 + cb * 16 + j];
            arv[cb] = ar3[cr * 128 + cb * 16 + j];
        }
        __syncthreads();

        f32x4 acc[2][8] = {};
        #pragma unroll
        for (int cb = 0; cb < 8; cb++) {
            int col = cb * 16 + j;
            const short* wp = Wl + col * 128;
            int sw = (col & 7) << 3;
            #pragma unroll
            for (int kk = 0; kk < 4; kk++) {
                short8v b = *(const short8v*)(wp + ((kk * 32 + q * 8) ^ sw));
                acc[0][cb] = __builtin_amdgcn_mfma_f32_16x16x32_bf16(a[0][kk], b, acc[0][cb], 0, 0, 0);
                acc[1][cb] = __builtin_amdgcn_mfma_f32_16x16x32_bf16(a[1][kk], b, acc[1][cb], 0, 0, 0);
            }
        }

        short* outB = featb + (size_t)cr * N_NODES * 128;
        #pragma unroll
        for (int rb = 0; rb < 2; rb++) {
            int row0 = rowbase + rb * 16 + q * 4;
            #pragma unroll
            for (int reg = 0; reg < 4; reg++) {
                int row = row0 + reg;
                if (row < nrows) {
                    short* op = outB + (size_t)row * 128 + j;
                    #pragma unroll
                    for (int cb = 0; cb < 8; cb++) op[cb * 16] = f2bf(acc[rb][cb][reg]);
                }
            }
        }

        // fused el/er
        float2* elo = el2 + (size_t)cr * N_NODES;
        float2* ero = er2 + (size_t)cr * N_NODES;
        #pragma unroll
        for (int rb = 0; rb < 2; rb++) {
            float e0[4], e1[4], r0[4], r1[4];
            #pragma unroll
            for (int reg = 0; reg < 4; reg++) {
                float se0 = 0.f, se1 = 0.f, sr0 = 0.f, sr1 = 0.f;
                #pragma unroll
                for (int cb = 0; cb < 4; cb++) {
                    se0 += acc[rb][cb][reg] * alv[cb];
                    sr0 += acc[rb][cb][reg] * arv[cb];
                    se1 += acc[rb][cb + 4][reg] * alv[cb + 4];
                    sr1 += acc[rb][cb + 4][reg] * arv[cb + 4];
                }
                #pragma unroll
                for (int off = 1; off < 16; off <<= 1) {
                    se0 += __shfl_xor(se0, off);
                    se1 += __shfl_xor(se1, off);
                    sr0 += __shfl_xor(sr0, off);
                    sr1 += __shfl_xor(sr1, off);
                }
                e0[reg] = se0; e1[reg] = se1; r0[reg] = sr0; r1[reg] = sr1;
            }
            if (j < 4) {
                int row = rowbase + rb * 16 + q * 4 + j;
                if (row < nrows) {
                    float2 ve, vr;
                    ve.x = j == 0 ? e0[0] : j == 1 ? e0[1] : j == 2 ? e0[2] : e0[3];
                    ve.y = j == 0 ? e1[0] : j == 1 ? e1[1] : j == 2 ? e1[2] : e1[3];
                    vr.x = j == 0 ? r0[0] : j == 1 ? r0[1] : j == 2 ? r0[2] : r0[3];
                    vr.y = j == 0 ? r1[0] : j == 1 ? r1[1] : j == 2 ? r1[2] : r1[3];
                    elo[row] = ve;
                    ero[row] = vr;
                }
            }
        }
    }
}

// ---------------- merged 3-relation softmax + gather-aggregate (wave per dst node) ----------------
// Concatenated lane space + scan-based per-relation softmax + prescaled packed alpha.
// el gathered from compact 2.4 MB float2 array (cache-dense); er read per dst node.
__global__ __launch_bounds__(256) void k_agg3(const short* __restrict__ feat,   // [3][N*128]
                                              const float2* __restrict__ el2,   // [3][N]
                                              const float2* __restrict__ er2,   // [3][N]
                                              const int* __restrict__ rowptr,   // [3][N+1]
                                              const int* __restrict__ csrc,     // [3][E]
                                              const float* __restrict__ bsum,   // [128] summed bias
                                              short* __restrict__ outB, int nrows) {
    int wid = threadIdx.x >> 6, lane = threadIdx.x & 63;
    int v = (blockIdx.x << 2) + wid;
    if (v >= nrows) return;
    int c0 = lane << 1;
    bool lo = lane < 32;
    unsigned psel = lo ? 0x01000404u : 0x03020404u;   // dest=[0,0,bk,bk+1] from s1 bytes

    int beg[3], deg[3];
    #pragma unroll
    for (int r = 0; r < 3; r++) {
        beg[r] = rowptr[r * (N_NODES + 1) + v];
        deg[r] = rowptr[r * (N_NODES + 1) + v + 1] - beg[r];
    }
    float2 er0v = er2[v];
    float2 er1v = er2[(size_t)N_NODES + v];
    float2 er2v = er2[(size_t)2 * N_NODES + v];
    int tc = deg[0] + deg[1] + deg[2];

    float2 bv = *(const float2*)(bsum + c0);
    float t0 = bv.x, t1 = bv.y;

    if (tc <= 64) {
        int b0 = deg[0], b01 = deg[0] + deg[1];
        int rsel = (lane >= b0 ? 1 : 0) + (lane >= b01 ? 1 : 0);
        int rofs = rsel == 0 ? 0 : (rsel == 1 ? b0 : b01);
        int idx = lane - rofs;
        bool val = lane < tc;
        float evz = rsel == 0 ? er0v.x : (rsel == 1 ? er1v.x : er2v.x);
        float evw = rsel == 0 ? er0v.y : (rsel == 1 ? er1v.y : er2v.y);
        int s = val ? csrc[(size_t)rsel * N_EDGES + beg[rsel] + idx] : 0;
        float2 es = el2[(size_t)rsel * N_NODES + s];
        float e0 = es.x + evz; e0 = e0 >= 0.f ? e0 : NEG_SLOPE * e0;
        float e1 = es.y + evw; e1 = e1 >= 0.f ? e1 : NEG_SLOPE * e1;
        float p0 = val ? __expf(e0) : 0.f;
        float p1 = val ? __expf(e1) : 0.f;

        // inclusive wave scan of (p0, p1)
        float s0 = p0, s1 = p1;
        #pragma unroll
        for (int d = 1; d < 64; d <<= 1) {
            float u0 = __shfl_up(s0, d), u1 = __shfl_up(s1, d);
            if (lane >= d) { s0 += u0; s1 += u1; }
        }
        // per-relation sums from scan boundaries (uniform indices)
        float E00 = (b0 > 0) ? rlf(s0, b0 - 1) : 0.f;
        float E01 = (b01 > b0) ? rlf(s0, b01 - 1) : E00;
        float E02 = (tc > b01) ? rlf(s0, tc - 1) : E01;
        float E10 = (b0 > 0) ? rlf(s1, b0 - 1) : 0.f;
        float E11 = (b01 > b0) ? rlf(s1, b01 - 1) : E10;
        float E12 = (tc > b01) ? rlf(s1, tc - 1) : E11;
        float m00 = E00, m01 = E01 - E00, m02 = E02 - E01;
        float m10 = E10, m11 = E11 - E10, m12 = E12 - E11;
        float i00 = m00 > 0.f ? frcp(m00) : 0.f;
        float i01 = m01 > 0.f ? frcp(m01) : 0.f;
        float i02 = m02 > 0.f ? frcp(m02) : 0.f;
        float i10 = m10 > 0.f ? frcp(m10) : 0.f;
        float i11 = m11 > 0.f ? frcp(m11) : 0.f;
        float i12 = m12 > 0.f ? frcp(m12) : 0.f;
        float iv0 = rsel == 0 ? i00 : (rsel == 1 ? i01 : i02);
        float iv1 = rsel == 0 ? i10 : (rsel == 1 ? i11 : i12);
        unsigned pkl = cvtpk(p0 * iv0, p1 * iv1);   // invalid lanes: p=0 -> 0 pack
        int addr = (rsel * N_NODES + s) << 7;   // element offset of feat row

        float xa = 0.f, xb = 0.f, ya = 0.f, yb = 0.f;
        for (int j0 = 0; j0 < tc; j0 += 4) {
            int a0_ = __builtin_amdgcn_readlane(addr, j0);
            int a1_ = __builtin_amdgcn_readlane(addr, j0 + 1);
            int a2_ = __builtin_amdgcn_readlane(addr, j0 + 2);
            int a3_ = __builtin_amdgcn_readlane(addr, j0 + 3);
            unsigned b0_ = (unsigned)__builtin_amdgcn_readlane((int)pkl, j0);
            unsigned b1_ = (unsigned)__builtin_amdgcn_readlane((int)pkl, j0 + 1);
            unsigned b2_ = (unsigned)__builtin_amdgcn_readlane((int)pkl, j0 + 2);
            unsigned b3_ = (unsigned)__builtin_amdgcn_readlane((int)pkl, j0 + 3);
            unsigned u0 = *(const unsigned*)(feat + (size_t)(unsigned)a0_ + c0);
            unsigned u1 = *(const unsigned*)(feat + (size_t)(unsigned)a1_ + c0);
            unsigned u2 = *(const unsigned*)(feat + (size_t)(unsigned)a2_ + c0);
            unsigned u3 = *(const unsigned*)(feat + (size_t)(unsigned)a3_ + c0);
            float q0 = asf(__builtin_amdgcn_perm(0u, b0_, psel));
            float q1 = asf(__builtin_amdgcn_perm(0u, b1_, psel));
            float q2 = asf(__builtin_amdgcn_perm(0u, b2_, psel));
            float q3 = asf(__builtin_amdgcn_perm(0u, b3_, psel));
            xa += q0 * bflo(u0); xb += q0 * bfhi(u0);
            ya += q1 * bflo(u1); yb += q1 * bfhi(u1);
            xa += q2 * bflo(u2); xb += q2 * bfhi(u2);
            ya += q3 * bflo(u3); yb += q3 * bfhi(u3);
        }
        t0 += xa + ya;
        t1 += xb + yb;
    } else {
        // generic fallback: per-relation, 64-chunked, sum + divide at end
        float evzs[3] = {er0v.x, er1v.x, er2v.x};
        float evws[3] = {er0v.y, er1v.y, er2v.y};
        #pragma unroll
        for (int r = 0; r < 3; r++) {
            const short* fb = feat + (size_t)r * (N_NODES * 128);
            float sp = 0.f, a0 = 0.f, a1 = 0.f;
            int e_end = beg[r] + deg[r];
            for (int base = beg[r]; base < e_end; base += 64) {
                int idx = base + lane;
                bool val = idx < e_end;
                int sv2 = val ? csrc[(size_t)r * N_EDGES + idx] : 0;
                float2 es = el2[(size_t)r * N_NODES + sv2];
                float e0 = es.x + evzs[r]; e0 = e0 >= 0.f ? e0 : NEG_SLOPE * e0;
                float e1 = es.y + evws[r]; e1 = e1 >= 0.f ? e1 : NEG_SLOPE * e1;
                float q0v = val ? __expf(e0) : 0.f;
                float q1v = val ? __expf(e1) : 0.f;
                int bcn = min(64, e_end - base);
                for (int k = 0; k < bcn; k++) {
                    int ss = __builtin_amdgcn_readlane(sv2, k);
                    float q0 = rlf(q0v, k), q1 = rlf(q1v, k);
                    float pp = lo ? q0 : q1;
                    unsigned u = *(const unsigned*)(fb + ((size_t)(unsigned)ss << 7) + c0);
                    sp += pp;
                    a0 += pp * bflo(u);
                    a1 += pp * bfhi(u);
                }
            }
            float inv = sp > 0.f ? frcp(sp) : 0.f;
            t0 += a0 * inv;
            t1 += a1 * inv;
        }
    }

    unsigned pko = cvtpk(fmaxf(t0, 0.f), fmaxf(t1, 0.f));
    *(unsigned*)(outB + (size_t)v * 128 + c0) = pko;
}

// ---------------- BN stats (bf16 relu'd input, vectorized) ----------------
__global__ __launch_bounds__(256) void k_bnstat(const short* __restrict__ h,
                                                float* __restrict__ sums, int nrows) {
    int tid = threadIdx.x;
    int cg = tid & 15, rgrp = tid >> 4;
    float s[8] = {}, q[8] = {};
    for (int row = blockIdx.x * 16 + rgrp; row < nrows; row += gridDim.x * 16) {
        short8v u = *(const short8v*)(h + (size_t)row * 128 + cg * 8);
        #pragma unroll
        for (int i = 0; i < 8; i++) {
            float x = bfs(u[i]);
            s[i] += x; q[i] += x * x;
        }
    }
    __shared__ float ls[16][128];
    __shared__ float lq[16][128];
    #pragma unroll
    for (int i = 0; i < 8; i++) { ls[rgrp][cg * 8 + i] = s[i]; lq[rgrp][cg * 8 + i] = q[i]; }
    __syncthreads();
    int t = tid;
    if (t < 128) {
        float ts = 0.f, tq = 0.f;
        #pragma unroll
        for (int g = 0; g < 16; g++) { ts += ls[g][t]; tq += lq[g][t]; }
        atomicAdd(&sums[t], ts);
        atomicAdd(&sums[128 + t], tq);
    }
}

// ---------------- classifier: BN-normalize (input pre-relu'd bf16) -> MFMA GEMM [N,128]x[128,64] ----------------
__global__ __launch_bounds__(256) void k_clf(const short* __restrict__ h,
                                             const float* __restrict__ sums,
                                             const float* __restrict__ bn_w,
                                             const float* __restrict__ bn_b,
                                             const short* __restrict__ Wcb,
                                             const float* __restrict__ cbias,
                                             float* __restrict__ out, int nrows) {
    __shared__ __align__(16) short Wl[64 * 128];
    __shared__ float2 bnp[128];
    int tid = threadIdx.x;
    {
        const float4* srcv = (const float4*)Wcb;
        float4* dstv = (float4*)Wl;
        #pragma unroll
        for (int i = 0; i < 4; i++) dstv[tid + i * 256] = srcv[tid + i * 256];
    }
    if (tid < 128) {
        float mu = sums[tid] / (float)nrows;
        float var = sums[128 + tid] / (float)nrows - mu * mu;
        float rs = rsqrtf(var + 1e-5f);
        float sc = bn_w[tid] * rs;
        bnp[tid] = make_float2(sc, bn_b[tid] - mu * sc);
    }
    __syncthreads();

    int lane = tid & 63, wid = tid >> 6;
    int q = lane >> 4, j = lane & 15;
    int rowbase = blockIdx.x * 128 + wid * 32;

    float cbv[4];
    #pragma unroll
    for (int cb = 0; cb < 4; cb++) cbv[cb] = cbias[cb * 16 + j];

    short8v a[2][4];
    #pragma unroll
    for (int rb = 0; rb < 2; rb++) {
        int row = rowbase + rb * 16 + j;
        bool ok = row < nrows;
        const short* hp = h + (size_t)row * 128 + q * 8;
        #pragma unroll
        for (int kk = 0; kk < 4; kk++) {
            short8v u = ok ? *(const short8v*)(hp + kk * 32) : (short8v)0;
            int k0 = kk * 32 + q * 8;
            short8v av;
            #pragma unroll
            for (int i = 0; i < 8; i++) {
                float2 bp = bnp[k0 + i];
                av[i] = f2bf(bfs(u[i]) * bp.x + bp.y);
            }
            a[rb][kk] = av;
        }
    }

    f32x4 acc[2][4] = {};
    #pragma unroll
    for (int cb = 0; cb < 4; cb++) {
        int col = cb * 16 + j;
        const short* wp = Wl + col * 128;
        int sw = (col & 7) << 3;
        #pragma unroll
        for (int kk = 0; kk < 4; kk++) {
            short8v b = *(const short8v*)(wp + ((kk * 32 + q * 8) ^ sw));
            acc[0][cb] = __builtin_amdgcn_mfma_f32_16x16x32_bf16(a[0][kk], b, acc[0][cb], 0, 0, 0);
            acc[1][cb] = __builtin_amdgcn_mfma_f32_16x16x32_bf16(a[1][kk], b, acc[1][cb], 0, 0, 0);
        }
    }

    #pragma unroll
    for (int rb = 0; rb < 2; rb++) {
        int row0 = rowbase + rb * 16 + q * 4;
        #pragma unroll
        for (int reg = 0; reg < 4; reg++) {
            int row = row0 + reg;
            if (row < nrows) {
                float* op = out + (size_t)row * 64 + j;
                #pragma unroll
                for (int cb = 0; cb < 4; cb++) op[cb * 16] = acc[rb][cb][reg] + cbv[cb];
            }
        }
    }
}

// ---------------- launch ----------------

extern "C" void kernel_launch(void* const* d_in, const int* in_sizes, int n_in,
                              void* d_out, int out_size, void* d_ws, size_t ws_size,
                              hipStream_t stream) {
    (void)in_sizes; (void)n_in; (void)out_size; (void)ws_size;
    const float* feat_in = (const float*)d_in[0];
    const float* Ws      = (const float*)d_in[1];
    const float* als     = (const float*)d_in[2];
    const float* ars     = (const float*)d_in[3];
    const float* bs      = (const float*)d_in[4];
    const float* bn_w    = (const float*)d_in[5];
    const float* bn_b    = (const float*)d_in[6];
    const float* clf_W   = (const float*)d_in[7];
    const float* clf_b   = (const float*)d_in[8];
    const int*   src     = (const int*)d_in[9];
    const int*   dst     = (const int*)d_in[10];
    float* out = (float*)d_out;

    const int N = N_NODES, E = N_EDGES;
    char* p = (char*)d_ws;
    auto carve = [&](size_t bytes) { char* q = p; p += (bytes + 255) & ~255ULL; return q; };
    int*      bcnt   = (int*)carve((size_t)3 * NB * 4);
    int*      bptr   = (int*)carve((size_t)3 * (NB + 1) * 4);
    int*      bcur   = (int*)carve((size_t)3 * NB * 4);
    int*      rowptr = (int*)carve((size_t)3 * (N + 1) * 4);
    int*      csrc   = (int*)carve((size_t)3 * E * 4);
    unsigned* ebin   = (unsigned*)carve((size_t)3 * E * 4);
    float2*   el2    = (float2*)carve((size_t)3 * N * 8);
    float2*   er2    = (float2*)carve((size_t)3 * N * 8);
    float*    bnsum  = (float*)carve(256 * 4);
    float*    bsum   = (float*)carve((size_t)2 * 128 * 4);
    short*    Wtg    = (short*)carve((size_t)6 * 16384 * 2);
    short*    Wcb    = (short*)carve((size_t)8192 * 2);
    short*    hA     = (short*)carve((size_t)N * 128 * 2);
    short*    hB     = (short*)carve((size_t)N * 128 * 2);
    short*    featb  = (short*)carve((size_t)3 * N * 128 * 2);

    // weight prep + input conversion
    k_wprep<<<(6 * 16384 + 255) / 256, 256, 0, stream>>>(Ws, Wtg);
    k_wprep2<<<(8192 + 256 + 255) / 256, 256, 0, stream>>>(clf_W, bs, Wcb, bsum);
    k_cvt<<<2048, 256, 0, stream>>>(feat_in, hA, N * 128);

    // CSR build via binned sort
    hipMemsetAsync(bcnt, 0, (size_t)3 * NB * 4, stream);
    dim3 gchunk((E + 4095) / 4096, 3);
    k_bhist<<<gchunk, 256, 0, stream>>>(dst, bcnt);
    k_bscan<<<3, 64, 0, stream>>>(bcnt, bptr, bcur);
    k_bin<<<gchunk, 256, 0, stream>>>(src, dst, bcur, ebin);
    dim3 gbkt(NB, 3);
    k_nhist<<<gbkt, 256, 0, stream>>>(ebin, bptr, rowptr);
    k_scat2<<<gbkt, 256, 0, stream>>>(ebin, bptr, rowptr, csrc);

    int gq = (N + 3) / 4;
    for (int l = 0; l < 2; l++) {
        const short* hin = (l == 0) ? hA : hB;
        short* hout = (l == 0) ? hB : hA;
        k_gemm3<<<(N + 127) / 128, 256, 0, stream>>>(hin, Wtg + (size_t)l * 3 * 16384,
                                                     als + (size_t)l * 384, ars + (size_t)l * 384,
                                                     featb, el2, er2, N);
        k_agg3<<<gq, 256, 0, stream>>>(featb, el2, er2, rowptr, csrc,
                                       bsum + (size_t)l * 128, hout, N);
    }

    // BN + classifier on hA (layer-2 output, relu'd bf16)
    hipMemsetAsync(bnsum, 0, 256 * 4, stream);
    k_bnstat<<<512, 256, 0, stream>>>(hA, bnsum, N);
    k_clf<<<(N + 127) / 128, 256, 0, stream>>>(hA, bnsum, bn_w, bn_b, Wcb, clf_b, out, N);
}

// Round 17
// 321.387 us; speedup vs baseline: 1.2281x; 1.0873x over previous
//
#include <hip/hip_runtime.h>
#include <hip/hip_bf16.h>

#define N_NODES 100000
#define N_EDGES 500000
#define HID 128
#define NEG_SLOPE 0.2f
#define NB 98           // buckets of 1024 nodes: ceil(100000/1024)

typedef __attribute__((ext_vector_type(8))) short short8v;
typedef __attribute__((ext_vector_type(4))) short short4v;
typedef __attribute__((ext_vector_type(4))) float f32x4;
typedef __attribute__((ext_vector_type(4))) unsigned uint4v;

__device__ __forceinline__ short f2bf(float x) {
    union { float f; unsigned u; } v; v.f = x;
    unsigned r = v.u + 0x7fff + ((v.u >> 16) & 1);  // RNE
    return (short)(r >> 16);
}
__device__ __forceinline__ unsigned cvtpk(float lo_, float hi_) {  // RNE pack: [bf16(lo) | bf16(hi)<<16]
    unsigned r;
    asm("v_cvt_pk_bf16_f32 %0, %1, %2" : "=v"(r) : "v"(lo_), "v"(hi_));
    return r;
}
__device__ __forceinline__ float frcp(float x) { return __builtin_amdgcn_rcpf(x); }
__device__ __forceinline__ float bflo(unsigned u) {
    union { unsigned x; float f; } c; c.x = u << 16; return c.f;
}
__device__ __forceinline__ float bfhi(unsigned u) {
    union { unsigned x; float f; } c; c.x = u & 0xffff0000u; return c.f;
}
__device__ __forceinline__ float bfs(short s) {
    union { unsigned x; float f; } c; c.x = ((unsigned)(unsigned short)s) << 16; return c.f;
}
__device__ __forceinline__ float asf(unsigned u) {
    union { unsigned x; float f; } c; c.x = u; return c.f;
}
__device__ __forceinline__ float rlf(float x, int i) {
    return asf((unsigned)__builtin_amdgcn_readlane((int)__float_as_uint(x), i));
}

// ---------------- CSR build: binned two-level sort ----------------

__global__ __launch_bounds__(256) void k_bhist(const int* __restrict__ dst, int* __restrict__ bcnt) {
    int r = blockIdx.y, tid = threadIdx.x;
    int base = blockIdx.x * 4096;
    __shared__ int h[128];
    if (tid < 128) h[tid] = 0;
    __syncthreads();
    size_t eb = (size_t)r * N_EDGES;
    int lim = min(base + 4096, N_EDGES);
    for (int e = base + tid; e < lim; e += 256) atomicAdd(&h[dst[eb + e] >> 10], 1);
    __syncthreads();
    if (tid < NB && h[tid]) atomicAdd(&bcnt[r * NB + tid], h[tid]);
}

__global__ void k_bscan(const int* __restrict__ bcnt, int* __restrict__ bptr, int* __restrict__ bcur) {
    int r = blockIdx.x, lane = threadIdx.x;
    int carry = 0;
    for (int base = 0; base < NB; base += 64) {
        int i = base + lane;
        int c = (i < NB) ? bcnt[r * NB + i] : 0;
        int v = c;
        #pragma unroll
        for (int d = 1; d < 64; d <<= 1) { int t = __shfl_up(v, d); if (lane >= d) v += t; }
        int excl = carry + v - c;
        if (i < NB) { bptr[r * (NB + 1) + i] = excl; bcur[r * NB + i] = excl; }
        carry += __shfl(v, 63);
    }
    if (lane == 0) bptr[r * (NB + 1) + NB] = carry;
}

// bin edges into bucket regions of ebin packed as ((dst&1023)<<17 | src)
__global__ __launch_bounds__(256) void k_bin(const int* __restrict__ src, const int* __restrict__ dst,
                                             int* __restrict__ bcur, unsigned* __restrict__ ebin) {
    int r = blockIdx.y, tid = threadIdx.x;
    int base = blockIdx.x * 4096;
    __shared__ int cnt[128], incl[128], gb[128], wcur[128];
    __shared__ uint2 stage[4096];
    if (tid < 128) cnt[tid] = 0;
    __syncthreads();
    int myd[16], mys[16];
    size_t eb = (size_t)r * N_EDGES;
    #pragma unroll
    for (int i = 0; i < 16; i++) {
        int e = base + i * 256 + tid;
        if (e < N_EDGES) {
            int d = dst[eb + e];
            myd[i] = d; mys[i] = src[eb + e];
            atomicAdd(&cnt[d >> 10], 1);
        } else myd[i] = -1;
    }
    __syncthreads();
    if (tid < 128) incl[tid] = cnt[tid];
    __syncthreads();
    for (int d = 1; d < 128; d <<= 1) {
        int t = 0;
        if (tid < 128 && tid >= d) t = incl[tid - d];
        __syncthreads();
        if (tid < 128 && tid >= d) incl[tid] += t;
        __syncthreads();
    }
    if (tid < 128) {
        wcur[tid] = incl[tid] - cnt[tid];
        gb[tid] = (tid < NB && cnt[tid] > 0) ? atomicAdd(&bcur[r * NB + tid], cnt[tid]) : 0;
    }
    __syncthreads();
    #pragma unroll
    for (int i = 0; i < 16; i++) {
        if (myd[i] >= 0) {
            int bkt = myd[i] >> 10;
            int p = atomicAdd(&wcur[bkt], 1);
            stage[p] = make_uint2((unsigned)myd[i], (unsigned)mys[i]);
        }
    }
    __syncthreads();
    int tot = min(4096, N_EDGES - base);
    for (int i = tid; i < tot; i += 256) {
        uint2 u = stage[i];
        int bkt = (int)(u.x >> 10);
        int ex = incl[bkt] - cnt[bkt];
        ebin[eb + gb[bkt] + (i - ex)] = ((u.x & 1023u) << 17) | u.y;
    }
}

// fused: per-bucket node histogram + local scan -> rowptr, then LDS-staged placement -> csrc
__global__ __launch_bounds__(256) void k_nscat(const unsigned* __restrict__ ebin,
                                               const int* __restrict__ bptr,
                                               int* __restrict__ rowptr,
                                               int* __restrict__ csrc) {
    int b = blockIdx.x, r = blockIdx.y, tid = threadIdx.x;
    __shared__ int cnt[1024];
    __shared__ int rloc[1024];
    __shared__ int stage[8192];
    __shared__ int wsum[4];
    for (int i = tid; i < 1024; i += 256) cnt[i] = 0;
    __syncthreads();
    int es = bptr[r * (NB + 1) + b], ee = bptr[r * (NB + 1) + b + 1];
    size_t eb = (size_t)r * N_EDGES;
    for (int i = es + tid; i < ee; i += 256) atomicAdd(&cnt[(ebin[eb + i] >> 17) & 1023u], 1);
    __syncthreads();
    int b4 = tid * 4;
    int c0 = cnt[b4], c1 = cnt[b4 + 1], c2 = cnt[b4 + 2], c3 = cnt[b4 + 3];
    int ts = c0 + c1 + c2 + c3;
    int lane = tid & 63, wid = tid >> 6;
    int v = ts;
    #pragma unroll
    for (int d = 1; d < 64; d <<= 1) { int t = __shfl_up(v, d); if (lane >= d) v += t; }
    if (lane == 63) wsum[wid] = v;
    __syncthreads();
    int woff = 0;
    for (int w = 0; w < wid; w++) woff += wsum[w];
    int p = woff + v - ts;   // exclusive local prefix for this thread's 4 nodes
    int node0 = b << 10;
    int rp = r * (N_NODES + 1);
    int nd, pl = p;
    nd = node0 + b4;     if (nd < N_NODES) rowptr[rp + nd] = es + pl; rloc[b4] = pl;     pl += c0;
    nd = node0 + b4 + 1; if (nd < N_NODES) rowptr[rp + nd] = es + pl; rloc[b4 + 1] = pl; pl += c1;
    nd = node0 + b4 + 2; if (nd < N_NODES) rowptr[rp + nd] = es + pl; rloc[b4 + 2] = pl; pl += c2;
    nd = node0 + b4 + 3; if (nd < N_NODES) rowptr[rp + nd] = es + pl; rloc[b4 + 3] = pl;
    if (b == NB - 1 && tid == 0) rowptr[rp + N_NODES] = bptr[r * (NB + 1) + NB];
    // reset cnt for rank atomics
    cnt[b4] = 0; cnt[b4 + 1] = 0; cnt[b4 + 2] = 0; cnt[b4 + 3] = 0;
    __syncthreads();
    int sz = ee - es;
    if (sz <= 8192) {
        for (int i = es + tid; i < ee; i += 256) {
            unsigned u = ebin[eb + i];
            int dl = (int)((u >> 17) & 1023u);
            int rk = atomicAdd(&cnt[dl], 1);
            stage[rloc[dl] + rk] = (int)(u & 0x1FFFFu);
        }
        __syncthreads();
        for (int i = tid; i < sz; i += 256) csrc[eb + es + i] = stage[i];
    } else {  // statistically unreachable fallback
        for (int i = es + tid; i < ee; i += 256) {
            unsigned u = ebin[eb + i];
            int dl = (int)((u >> 17) & 1023u);
            int rk = atomicAdd(&cnt[dl], 1);
            csrc[eb + es + rloc[dl] + rk] = (int)(u & 0x1FFFFu);
        }
    }
}

// ---------------- W prep: f32 [k][col] -> bf16 [col][k ^ ((col&7)<<3)] ----------------
__global__ void k_wprep(const float* __restrict__ Ws, short* __restrict__ Wt) {
    int i = blockIdx.x * blockDim.x + threadIdx.x;
    if (i < 6 * 16384) {
        int lr = i >> 14, rem = i & 16383, k = rem >> 7, col = rem & 127;
        Wt[lr * 16384 + col * 128 + (k ^ ((col & 7) << 3))] = f2bf(Ws[i]);
    }
}

// clf_W f32 [128 k][64 col] -> bf16 [col][k ^ ((col&7)<<3)]; also bias sums per layer
__global__ void k_wprep2(const float* __restrict__ Wc, const float* __restrict__ bs,
                         short* __restrict__ Wcb, float* __restrict__ bsum) {
    int i = blockIdx.x * blockDim.x + threadIdx.x;
    if (i < 8192) {
        int k = i >> 6, col = i & 63;
        Wcb[col * 128 + (k ^ ((col & 7) << 3))] = f2bf(Wc[i]);
    } else if (i < 8192 + 256) {
        int j = i - 8192;
        int l = j >> 7, c = j & 127;
        bsum[j] = bs[(l * 3 + 0) * 128 + c] + bs[(l * 3 + 1) * 128 + c] + bs[(l * 3 + 2) * 128 + c];
    }
}

// ---------------- MFMA GEMM over 3 relations in one dispatch: featb[r] bf16 + fused el/er ----------------
// A source: Af32 (layer 0, f32 input, converted in-register) or Abf (bf16).
__global__ __launch_bounds__(256) void k_gemm3(const short* __restrict__ Abf,
                                               const float* __restrict__ Af32,
                                               const short* __restrict__ Wt3,    // 3 x 16384, pre-swizzled
                                               const float* __restrict__ al3,    // [3][128]
                                               const float* __restrict__ ar3,    // [3][128]
                                               short* __restrict__ featb,        // [3][N*128]
                                               float2* __restrict__ el2,         // [3][N]
                                               float2* __restrict__ er2,         // [3][N]
                                               int nrows) {
    __shared__ __align__(16) short Wl[128 * 128];
    int tid = threadIdx.x;
    int lane = tid & 63, wid = tid >> 6;
    int q = lane >> 4, j = lane & 15;
    int rowbase = blockIdx.x * 128 + wid * 32;

    // A fragments once (shared by all 3 relations)
    short8v a[2][4];
    #pragma unroll
    for (int rb = 0; rb < 2; rb++) {
        int row = rowbase + rb * 16 + j;
        bool ok = row < nrows;
        if (Af32) {
            const float* ap = Af32 + (size_t)row * 128 + q * 8;
            #pragma unroll
            for (int kk = 0; kk < 4; kk++) {
                union { short8v s; uint4v u; } c;
                if (ok) {
                    float4 x = *(const float4*)(ap + kk * 32);
                    float4 y = *(const float4*)(ap + kk * 32 + 4);
                    c.u[0] = cvtpk(x.x, x.y); c.u[1] = cvtpk(x.z, x.w);
                    c.u[2] = cvtpk(y.x, y.y); c.u[3] = cvtpk(y.z, y.w);
                } else c.s = (short8v)0;
                a[rb][kk] = c.s;
            }
        } else {
            const short* ap = Abf + (size_t)row * 128 + q * 8;
            #pragma unroll
            for (int kk = 0; kk < 4; kk++)
                a[rb][kk] = ok ? *(const short8v*)(ap + kk * 32) : (short8v)0;
        }
    }

    for (int cr = 0; cr < 3; cr++) {
        if (cr) __syncthreads();   // all waves done reading Wl before overwrite
        {
            const float4* srcv = (const float4*)(Wt3 + cr * 16384);
            float4* dstv = (float4*)Wl;
            #pragma unroll
            for (int i = 0; i < 8; i++) dstv[tid + i * 256] = srcv[tid + i * 256];
        }
        float alv[8], arv[8];
        #pragma unroll
        for (int cb = 0; cb < 8; cb++) {
            alv[cb] = al3[cr * 128 + cb * 16 + j];
            arv[cb] = ar3[cr * 128 + cb * 16 + j];
        }
        __syncthreads();

        f32x4 acc[2][8] = {};
        #pragma unroll
        for (int cb = 0; cb < 8; cb++) {
            int col = cb * 16 + j;
            const short* wp = Wl + col * 128;
            int sw = (col & 7) << 3;
            #pragma unroll
            for (int kk = 0; kk < 4; kk++) {
                short8v b = *(const short8v*)(wp + ((kk * 32 + q * 8) ^ sw));
                acc[0][cb] = __builtin_amdgcn_mfma_f32_16x16x32_bf16(a[0][kk], b, acc[0][cb], 0, 0, 0);
                acc[1][cb] = __builtin_amdgcn_mfma_f32_16x16x32_bf16(a[1][kk], b, acc[1][cb], 0, 0, 0);
            }
        }

        short* outB = featb + (size_t)cr * N_NODES * 128;
        #pragma unroll
        for (int rb = 0; rb < 2; rb++) {
            int row0 = rowbase + rb * 16 + q * 4;
            #pragma unroll
            for (int reg = 0; reg < 4; reg++) {
                int row = row0 + reg;
                if (row < nrows) {
                    short* op = outB + (size_t)row * 128 + j;
                    #pragma unroll
                    for (int cb = 0; cb < 8; cb++) op[cb * 16] = f2bf(acc[rb][cb][reg]);
                }
            }
        }

        // fused el/er
        float2* elo = el2 + (size_t)cr * N_NODES;
        float2* ero = er2 + (size_t)cr * N_NODES;
        #pragma unroll
        for (int rb = 0; rb < 2; rb++) {
            float e0[4], e1[4], r0[4], r1[4];
            #pragma unroll
            for (int reg = 0; reg < 4; reg++) {
                float se0 = 0.f, se1 = 0.f, sr0 = 0.f, sr1 = 0.f;
                #pragma unroll
                for (int cb = 0; cb < 4; cb++) {
                    se0 += acc[rb][cb][reg] * alv[cb];
                    sr0 += acc[rb][cb][reg] * arv[cb];
                    se1 += acc[rb][cb + 4][reg] * alv[cb + 4];
                    sr1 += acc[rb][cb + 4][reg] * arv[cb + 4];
                }
                #pragma unroll
                for (int off = 1; off < 16; off <<= 1) {
                    se0 += __shfl_xor(se0, off);
                    se1 += __shfl_xor(se1, off);
                    sr0 += __shfl_xor(sr0, off);
                    sr1 += __shfl_xor(sr1, off);
                }
                e0[reg] = se0; e1[reg] = se1; r0[reg] = sr0; r1[reg] = sr1;
            }
            if (j < 4) {
                int row = rowbase + rb * 16 + q * 4 + j;
                if (row < nrows) {
                    float2 ve, vr;
                    ve.x = j == 0 ? e0[0] : j == 1 ? e0[1] : j == 2 ? e0[2] : e0[3];
                    ve.y = j == 0 ? e1[0] : j == 1 ? e1[1] : j == 2 ? e1[2] : e1[3];
                    vr.x = j == 0 ? r0[0] : j == 1 ? r0[1] : j == 2 ? r0[2] : r0[3];
                    vr.y = j == 0 ? r1[0] : j == 1 ? r1[1] : j == 2 ? r1[2] : r1[3];
                    elo[row] = ve;
                    ero[row] = vr;
                }
            }
        }
    }
}

// ---------------- merged 3-relation softmax + gather-aggregate (wave per dst node) ----------------
__global__ __launch_bounds__(256) void k_agg3(const short* __restrict__ feat,   // [3][N*128]
                                              const float2* __restrict__ el2,   // [3][N]
                                              const float2* __restrict__ er2,   // [3][N]
                                              const int* __restrict__ rowptr,   // [3][N+1]
                                              const int* __restrict__ csrc,     // [3][E]
                                              const float* __restrict__ bsum,   // [128] summed bias
                                              short* __restrict__ outB, int nrows) {
    int wid = threadIdx.x >> 6, lane = threadIdx.x & 63;
    int v = (blockIdx.x << 2) + wid;
    if (v >= nrows) return;
    int c0 = lane << 1;
    bool lo = lane < 32;
    unsigned psel = lo ? 0x01000404u : 0x03020404u;   // dest=[0,0,bk,bk+1] from s1 bytes

    int beg[3], deg[3];
    #pragma unroll
    for (int r = 0; r < 3; r++) {
        beg[r] = rowptr[r * (N_NODES + 1) + v];
        deg[r] = rowptr[r * (N_NODES + 1) + v + 1] - beg[r];
    }
    float2 er0v = er2[v];
    float2 er1v = er2[(size_t)N_NODES + v];
    float2 er2v = er2[(size_t)2 * N_NODES + v];
    int tc = deg[0] + deg[1] + deg[2];

    float2 bv = *(const float2*)(bsum + c0);
    float t0 = bv.x, t1 = bv.y;

    if (tc <= 64) {
        int b0 = deg[0], b01 = deg[0] + deg[1];
        int rsel = (lane >= b0 ? 1 : 0) + (lane >= b01 ? 1 : 0);
        int rofs = rsel == 0 ? 0 : (rsel == 1 ? b0 : b01);
        int idx = lane - rofs;
        bool val = lane < tc;
        float evz = rsel == 0 ? er0v.x : (rsel == 1 ? er1v.x : er2v.x);
        float evw = rsel == 0 ? er0v.y : (rsel == 1 ? er1v.y : er2v.y);
        int s = val ? csrc[(size_t)rsel * N_EDGES + beg[rsel] + idx] : 0;
        float2 es = el2[(size_t)rsel * N_NODES + s];
        float e0 = es.x + evz; e0 = e0 >= 0.f ? e0 : NEG_SLOPE * e0;
        float e1 = es.y + evw; e1 = e1 >= 0.f ? e1 : NEG_SLOPE * e1;
        float p0 = val ? __expf(e0) : 0.f;
        float p1 = val ? __expf(e1) : 0.f;

        // inclusive wave scan of (p0, p1)
        float s0 = p0, s1 = p1;
        #pragma unroll
        for (int d = 1; d < 64; d <<= 1) {
            float u0 = __shfl_up(s0, d), u1 = __shfl_up(s1, d);
            if (lane >= d) { s0 += u0; s1 += u1; }
        }
        // per-relation sums from scan boundaries (uniform indices)
        float E00 = (b0 > 0) ? rlf(s0, b0 - 1) : 0.f;
        float E01 = (b01 > b0) ? rlf(s0, b01 - 1) : E00;
        float E02 = (tc > b01) ? rlf(s0, tc - 1) : E01;
        float E10 = (b0 > 0) ? rlf(s1, b0 - 1) : 0.f;
        float E11 = (b01 > b0) ? rlf(s1, b01 - 1) : E10;
        float E12 = (tc > b01) ? rlf(s1, tc - 1) : E11;
        float m00 = E00, m01 = E01 - E00, m02 = E02 - E01;
        float m10 = E10, m11 = E11 - E10, m12 = E12 - E11;
        float i00 = m00 > 0.f ? frcp(m00) : 0.f;
        float i01 = m01 > 0.f ? frcp(m01) : 0.f;
        float i02 = m02 > 0.f ? frcp(m02) : 0.f;
        float i10 = m10 > 0.f ? frcp(m10) : 0.f;
        float i11 = m11 > 0.f ? frcp(m11) : 0.f;
        float i12 = m12 > 0.f ? frcp(m12) : 0.f;
        float iv0 = rsel == 0 ? i00 : (rsel == 1 ? i01 : i02);
        float iv1 = rsel == 0 ? i10 : (rsel == 1 ? i11 : i12);
        unsigned pkl = cvtpk(p0 * iv0, p1 * iv1);   // invalid lanes: p=0 -> 0 pack
        int addr = (rsel * N_NODES + s) << 7;   // element offset of feat row

        float xa = 0.f, xb = 0.f, ya = 0.f, yb = 0.f;
        for (int j0 = 0; j0 < tc; j0 += 4) {
            int a0_ = __builtin_amdgcn_readlane(addr, j0);
            int a1_ = __builtin_amdgcn_readlane(addr, j0 + 1);
            int a2_ = __builtin_amdgcn_readlane(addr, j0 + 2);
            int a3_ = __builtin_amdgcn_readlane(addr, j0 + 3);
            unsigned b0_ = (unsigned)__builtin_amdgcn_readlane((int)pkl, j0);
            unsigned b1_ = (unsigned)__builtin_amdgcn_readlane((int)pkl, j0 + 1);
            unsigned b2_ = (unsigned)__builtin_amdgcn_readlane((int)pkl, j0 + 2);
            unsigned b3_ = (unsigned)__builtin_amdgcn_readlane((int)pkl, j0 + 3);
            unsigned u0 = *(const unsigned*)(feat + (size_t)(unsigned)a0_ + c0);
            unsigned u1 = *(const unsigned*)(feat + (size_t)(unsigned)a1_ + c0);
            unsigned u2 = *(const unsigned*)(feat + (size_t)(unsigned)a2_ + c0);
            unsigned u3 = *(const unsigned*)(feat + (size_t)(unsigned)a3_ + c0);
            float q0 = asf(__builtin_amdgcn_perm(0u, b0_, psel));
            float q1 = asf(__builtin_amdgcn_perm(0u, b1_, psel));
            float q2 = asf(__builtin_amdgcn_perm(0u, b2_, psel));
            float q3 = asf(__builtin_amdgcn_perm(0u, b3_, psel));
            xa += q0 * bflo(u0); xb += q0 * bfhi(u0);
            ya += q1 * bflo(u1); yb += q1 * bfhi(u1);
            xa += q2 * bflo(u2); xb += q2 * bfhi(u2);
            ya += q3 * bflo(u3); yb += q3 * bfhi(u3);
        }
        t0 += xa + ya;
        t1 += xb + yb;
    } else {
        // generic fallback: per-relation, 64-chunked, sum + divide at end
        float evzs[3] = {er0v.x, er1v.x, er2v.x};
        float evws[3] = {er0v.y, er1v.y, er2v.y};
        #pragma unroll
        for (int r = 0; r < 3; r++) {
            const short* fb = feat + (size_t)r * (N_NODES * 128);
            float sp = 0.f, a0 = 0.f, a1 = 0.f;
            int e_end = beg[r] + deg[r];
            for (int base = beg[r]; base < e_end; base += 64) {
                int idx = base + lane;
                bool val = idx < e_end;
                int sv2 = val ? csrc[(size_t)r * N_EDGES + idx] : 0;
                float2 es = el2[(size_t)r * N_NODES + sv2];
                float e0 = es.x + evzs[r]; e0 = e0 >= 0.f ? e0 : NEG_SLOPE * e0;
                float e1 = es.y + evws[r]; e1 = e1 >= 0.f ? e1 : NEG_SLOPE * e1;
                float q0v = val ? __expf(e0) : 0.f;
                float q1v = val ? __expf(e1) : 0.f;
                int bcn = min(64, e_end - base);
                for (int k = 0; k < bcn; k++) {
                    int ss = __builtin_amdgcn_readlane(sv2, k);
                    float q0 = rlf(q0v, k), q1 = rlf(q1v, k);
                    float pp = lo ? q0 : q1;
                    unsigned u = *(const unsigned*)(fb + ((size_t)(unsigned)ss << 7) + c0);
                    sp += pp;
                    a0 += pp * bflo(u);
                    a1 += pp * bfhi(u);
                }
            }
            float inv = sp > 0.f ? frcp(sp) : 0.f;
            t0 += a0 * inv;
            t1 += a1 * inv;
        }
    }

    unsigned pko = cvtpk(fmaxf(t0, 0.f), fmaxf(t1, 0.f));
    *(unsigned*)(outB + (size_t)v * 128 + c0) = pko;
}

// ---------------- BN stats (bf16 relu'd input, vectorized) ----------------
__global__ __launch_bounds__(256) void k_bnstat(const short* __restrict__ h,
                                                float* __restrict__ sums, int nrows) {
    int tid = threadIdx.x;
    int cg = tid & 15, rgrp = tid >> 4;
    float s[8] = {}, q[8] = {};
    for (int row = blockIdx.x * 16 + rgrp; row < nrows; row += gridDim.x * 16) {
        short8v u = *(const short8v*)(h + (size_t)row * 128 + cg * 8);
        #pragma unroll
        for (int i = 0; i < 8; i++) {
            float x = bfs(u[i]);
            s[i] += x; q[i] += x * x;
        }
    }
    __shared__ float ls[16][128];
    __shared__ float lq[16][128];
    #pragma unroll
    for (int i = 0; i < 8; i++) { ls[rgrp][cg * 8 + i] = s[i]; lq[rgrp][cg * 8 + i] = q[i]; }
    __syncthreads();
    int t = tid;
    if (t < 128) {
        float ts = 0.f, tq = 0.f;
        #pragma unroll
        for (int g = 0; g < 16; g++) { ts += ls[g][t]; tq += lq[g][t]; }
        atomicAdd(&sums[t], ts);
        atomicAdd(&sums[128 + t], tq);
    }
}

// ---------------- classifier: BN-normalize (input pre-relu'd bf16) -> MFMA GEMM [N,128]x[128,64] ----------------
__global__ __launch_bounds__(256) void k_clf(const short* __restrict__ h,
                                             const float* __restrict__ sums,
                                             const float* __restrict__ bn_w,
                                             const float* __restrict__ bn_b,
                                             const short* __restrict__ Wcb,
                                             const float* __restrict__ cbias,
                                             float* __restrict__ out, int nrows) {
    __shared__ __align__(16) short Wl[64 * 128];
    __shared__ float2 bnp[128];
    int tid = threadIdx.x;
    {
        const float4* srcv = (const float4*)Wcb;
        float4* dstv = (float4*)Wl;
        #pragma unroll
        for (int i = 0; i < 4; i++) dstv[tid + i * 256] = srcv[tid + i * 256];
    }
    if (tid < 128) {
        float mu = sums[tid] / (float)nrows;
        float var = sums[128 + tid] / (float)nrows - mu * mu;
        float rs = rsqrtf(var + 1e-5f);
        float sc = bn_w[tid] * rs;
        bnp[tid] = make_float2(sc, bn_b[tid] - mu * sc);
    }
    __syncthreads();

    int lane = tid & 63, wid = tid >> 6;
    int q = lane >> 4, j = lane & 15;
    int rowbase = blockIdx.x * 128 + wid * 32;

    float cbv[4];
    #pragma unroll
    for (int cb = 0; cb < 4; cb++) cbv[cb] = cbias[cb * 16 + j];

    short8v a[2][4];
    #pragma unroll
    for (int rb = 0; rb < 2; rb++) {
        int row = rowbase + rb * 16 + j;
        bool ok = row < nrows;
        const short* hp = h + (size_t)row * 128 + q * 8;
        #pragma unroll
        for (int kk = 0; kk < 4; kk++) {
            short8v u = ok ? *(const short8v*)(hp + kk * 32) : (short8v)0;
            int k0 = kk * 32 + q * 8;
            short8v av;
            #pragma unroll
            for (int i = 0; i < 8; i++) {
                float2 bp = bnp[k0 + i];
                av[i] = f2bf(bfs(u[i]) * bp.x + bp.y);
            }
            a[rb][kk] = av;
        }
    }

    f32x4 acc[2][4] = {};
    #pragma unroll
    for (int cb = 0; cb < 4; cb++) {
        int col = cb * 16 + j;
        const short* wp = Wl + col * 128;
        int sw = (col & 7) << 3;
        #pragma unroll
        for (int kk = 0; kk < 4; kk++) {
            short8v b = *(const short8v*)(wp + ((kk * 32 + q * 8) ^ sw));
            acc[0][cb] = __builtin_amdgcn_mfma_f32_16x16x32_bf16(a[0][kk], b, acc[0][cb], 0, 0, 0);
            acc[1][cb] = __builtin_amdgcn_mfma_f32_16x16x32_bf16(a[1][kk], b, acc[1][cb], 0, 0, 0);
        }
    }

    #pragma unroll
    for (int rb = 0; rb < 2; rb++) {
        int row0 = rowbase + rb * 16 + q * 4;
        #pragma unroll
        for (int reg = 0; reg < 4; reg++) {
            int row = row0 + reg;
            if (row < nrows) {
                float* op = out + (size_t)row * 64 + j;
                #pragma unroll
                for (int cb = 0; cb < 4; cb++) op[cb * 16] = acc[rb][cb][reg] + cbv[cb];
            }
        }
    }
}

// ---------------- launch ----------------

extern "C" void kernel_launch(void* const* d_in, const int* in_sizes, int n_in,
                              void* d_out, int out_size, void* d_ws, size_t ws_size,
                              hipStream_t stream) {
    (void)in_sizes; (void)n_in; (void)out_size; (void)ws_size;
    const float* feat_in = (const float*)d_in[0];
    const float* Ws      = (const float*)d_in[1];
    const float* als     = (const float*)d_in[2];
    const float* ars     = (const float*)d_in[3];
    const float* bs      = (const float*)d_in[4];
    const float* bn_w    = (const float*)d_in[5];
    const float* bn_b    = (const float*)d_in[6];
    const float* clf_W   = (const float*)d_in[7];
    const float* clf_b   = (const float*)d_in[8];
    const int*   src     = (const int*)d_in[9];
    const int*   dst     = (const int*)d_in[10];
    float* out = (float*)d_out;

    const int N = N_NODES, E = N_EDGES;
    char* p = (char*)d_ws;
    auto carve = [&](size_t bytes) { char* q = p; p += (bytes + 255) & ~255ULL; return q; };
    int*      bcnt   = (int*)carve((size_t)3 * NB * 4);
    int*      bptr   = (int*)carve((size_t)3 * (NB + 1) * 4);
    int*      bcur   = (int*)carve((size_t)3 * NB * 4);
    int*      rowptr = (int*)carve((size_t)3 * (N + 1) * 4);
    int*      csrc   = (int*)carve((size_t)3 * E * 4);
    unsigned* ebin   = (unsigned*)carve((size_t)3 * E * 4);
    float2*   el2    = (float2*)carve((size_t)3 * N * 8);
    float2*   er2    = (float2*)carve((size_t)3 * N * 8);
    float*    bnsum  = (float*)carve(256 * 4);
    float*    bsum   = (float*)carve((size_t)2 * 128 * 4);
    short*    Wtg    = (short*)carve((size_t)6 * 16384 * 2);
    short*    Wcb    = (short*)carve((size_t)8192 * 2);
    short*    hA     = (short*)carve((size_t)N * 128 * 2);
    short*    hB     = (short*)carve((size_t)N * 128 * 2);
    short*    featb  = (short*)carve((size_t)3 * N * 128 * 2);

    // weight prep
    k_wprep<<<(6 * 16384 + 255) / 256, 256, 0, stream>>>(Ws, Wtg);
    k_wprep2<<<(8192 + 256 + 255) / 256, 256, 0, stream>>>(clf_W, bs, Wcb, bsum);

    // CSR build via binned sort
    hipMemsetAsync(bcnt, 0, (size_t)3 * NB * 4, stream);
    dim3 gchunk((E + 4095) / 4096, 3);
    k_bhist<<<gchunk, 256, 0, stream>>>(dst, bcnt);
    k_bscan<<<3, 64, 0, stream>>>(bcnt, bptr, bcur);
    k_bin<<<gchunk, 256, 0, stream>>>(src, dst, bcur, ebin);
    dim3 gbkt(NB, 3);
    k_nscat<<<gbkt, 256, 0, stream>>>(ebin, bptr, rowptr, csrc);

    int gq = (N + 3) / 4;
    // layer 0: A from f32 input directly
    k_gemm3<<<(N + 127) / 128, 256, 0, stream>>>(nullptr, feat_in, Wtg,
                                                 als, ars, featb, el2, er2, N);
    k_agg3<<<gq, 256, 0, stream>>>(featb, el2, er2, rowptr, csrc, bsum, hB, N);
    // layer 1: A from bf16 hB
    k_gemm3<<<(N + 127) / 128, 256, 0, stream>>>(hB, nullptr, Wtg + 3 * 16384,
                                                 als + 384, ars + 384, featb, el2, er2, N);
    k_agg3<<<gq, 256, 0, stream>>>(featb, el2, er2, rowptr, csrc, bsum + 128, hA, N);

    // BN + classifier on hA (layer-2 output, relu'd bf16)
    hipMemsetAsync(bnsum, 0, 256 * 4, stream);
    k_bnstat<<<512, 256, 0, stream>>>(hA, bnsum, N);
    k_clf<<<(N + 127) / 128, 256, 0, stream>>>(hA, bnsum, bn_w, bn_b, Wcb, clf_b, out, N);
}